// Round 3
// baseline (1167.424 us; speedup 1.0000x reference)
//
#include <hip/hip_runtime.h>
#include <math.h>
#include <stdint.h>

#define BB 2
#define TT 4
#define NQ 576
#define NKV 576
#define DD 1024
#define HH 16
#define DH 64
#define BT (BB*TT)          // 8
#define NTOK (BT*NQ)        // 4608
#define NEGV (-(3.402823466e38f) * 0.5f)   // == np.finfo(f32).min / 2, exact

// ---------------------------------------------------------------------------
// Mask canonicalization: the harness may upload bool masks as int32 (per ABI
// doc "integer -> const int*") or as raw 1-byte bools. Detect which: in int32
// little-endian encoding, every byte at j%4!=0 is zero; in uint8 encoding
// ~50% of those positions are 1. Only reads the first 4608 bytes (in-bounds
// under both encodings). Writes canonical uint8 masks.
// ---------------------------------------------------------------------------
__global__ __launch_bounds__(256) void canon_masks_kernel(
    const uint8_t* __restrict__ qm_raw, const uint8_t* __restrict__ km_raw,
    uint8_t* __restrict__ qm_out, uint8_t* __restrict__ km_out)
{
    __shared__ int flag_s;
    const int tid = threadIdx.x;          // single block of 256
    if (tid == 0) flag_s = 0;
    __syncthreads();
    int local = 0;
    for (int j = tid; j < NTOK; j += 256) {
        if ((j & 3) != 0 && (qm_raw[j] | km_raw[j])) local = 1;
    }
    if (local) atomicOr(&flag_s, 1);
    __syncthreads();
    const int is_u8 = flag_s;             // 1 => raw uint8 bools, 0 => int32
    const int* qi32 = (const int*)qm_raw;
    const int* ki32 = (const int*)km_raw;
    for (int j = tid; j < NTOK; j += 256) {
        qm_out[j] = is_u8 ? qm_raw[j] : (uint8_t)(qi32[j] != 0);
        km_out[j] = is_u8 ? km_raw[j] : (uint8_t)(ki32[j] != 0);
    }
}

// ---------------------------------------------------------------------------
// cos/sin tables: cs[(bt*576+n)*32 + i] = (cos(arg), sin(arg))
// arg = (0.5*pi) * coords[...,axis] * freq[axis][i']
// ---------------------------------------------------------------------------
__global__ __launch_bounds__(256) void build_cs_kernel(
    const float* __restrict__ cq, const float* __restrict__ ck,
    const float* __restrict__ f0, const float* __restrict__ f1,
    const float* __restrict__ f2,
    float2* __restrict__ csq, float2* __restrict__ csk)
{
    const int PER = NTOK * 32;              // 147456
    int idx = blockIdx.x * 256 + threadIdx.x;   // total = 2*PER = 294912 exact
    int half = idx / PER;
    int r = idx - half * PER;
    int i = r & 31;
    int tok = r >> 5;                        // [0, 4608)
    int axis; float f;
    if (i < 12)      { axis = 0; f = f0[i];      }
    else if (i < 22) { axis = 1; f = f1[i - 12]; }
    else             { axis = 2; f = f2[i - 22]; }
    const float* C = half ? ck : cq;
    float c = C[tok * 3 + axis];
    // match np: ((0.5*pi as f32) * c) * f, no contraction
    float arg = __fmul_rn(__fmul_rn(1.57079632679489662f, c), f);
    float s, co;
    __sincosf(arg, &s, &co);   // args in [0, pi/2): fast path is plenty accurate
    float2 out; out.x = co; out.y = s;
    (half ? csk : csq)[tok * 32 + i] = out;
}

// ---------------------------------------------------------------------------
// GEMM: O[m,n] = sum_k X[m,k]*W[n,k] + b[n]   (M=4608, N=K=1024)
// mode 0: store to [bt, h, n_tok, dh] layout (projections)
// mode 1: store row-major [m, 1024] (final output)
// ---------------------------------------------------------------------------
__global__ __launch_bounds__(256) void gemm_xwT_kernel(
    const float* __restrict__ X, const float* __restrict__ W,
    const float* __restrict__ bias, float* __restrict__ O, const int mode)
{
    __shared__ float Xs[16][68];
    __shared__ float Ws[16][68];
    const int tid = threadIdx.x;
    const int tx = tid & 15, ty = tid >> 4;
    const int m0 = blockIdx.y * 64, n0 = blockIdx.x * 64;
    const int row = tid >> 2, kq = (tid & 3) * 4;
    const float* Xp = X + (size_t)(m0 + row) * DD + kq;
    const float* Wp = W + (size_t)(n0 + row) * DD + kq;
    float acc[4][4] = {};
    for (int k0 = 0; k0 < DD; k0 += 16) {
        float4 xv = *(const float4*)(Xp + k0);
        float4 wv = *(const float4*)(Wp + k0);
        __syncthreads();
        Xs[kq + 0][row] = xv.x; Xs[kq + 1][row] = xv.y;
        Xs[kq + 2][row] = xv.z; Xs[kq + 3][row] = xv.w;
        Ws[kq + 0][row] = wv.x; Ws[kq + 1][row] = wv.y;
        Ws[kq + 2][row] = wv.z; Ws[kq + 3][row] = wv.w;
        __syncthreads();
#pragma unroll
        for (int kk = 0; kk < 16; kk++) {
            float4 a = *(const float4*)&Xs[kk][ty * 4];
            float4 b = *(const float4*)&Ws[kk][tx * 4];
            acc[0][0] += a.x*b.x; acc[0][1] += a.x*b.y; acc[0][2] += a.x*b.z; acc[0][3] += a.x*b.w;
            acc[1][0] += a.y*b.x; acc[1][1] += a.y*b.y; acc[1][2] += a.y*b.z; acc[1][3] += a.y*b.w;
            acc[2][0] += a.z*b.x; acc[2][1] += a.z*b.y; acc[2][2] += a.z*b.z; acc[2][3] += a.z*b.w;
            acc[3][0] += a.w*b.x; acc[3][1] += a.w*b.y; acc[3][2] += a.w*b.z; acc[3][3] += a.w*b.w;
        }
    }
#pragma unroll
    for (int i = 0; i < 4; i++) {
        int m = m0 + ty * 4 + i;
        int bt = m / NQ, nn = m - bt * NQ;
#pragma unroll
        for (int j = 0; j < 4; j++) {
            int n = n0 + tx * 4 + j;
            float v = acc[i][j] + bias[n];
            if (mode == 0) {
                int h = n >> 6, dh = n & 63;
                O[(((size_t)(bt * HH + h)) * NQ + nn) * DH + dh] = v;
            } else {
                O[(size_t)m * DD + n] = v;
            }
        }
    }
}

// ---------------------------------------------------------------------------
// RoPE in place on Qr/Kr ([bt,h,n,64] layout). One thread per rotation pair.
// ---------------------------------------------------------------------------
__global__ __launch_bounds__(256) void rope_kernel(
    float* __restrict__ Qr, float* __restrict__ Kr,
    const float2* __restrict__ csq, const float2* __restrict__ csk)
{
    const int PER = BT * HH * NQ * 32;       // 2359296
    int idx = blockIdx.x * 256 + threadIdx.x; // total 2*PER = 4718592 exact
    int half = idx / PER;                    // block-uniform (PER % 256 == 0)
    int r = idx - half * PER;
    int i = r & 31;
    int n = (r >> 5) % NQ;
    int rest = (r >> 5) / NQ;
    int h = rest & (HH - 1);
    int bt = rest >> 4;
    float2 cs = (half ? csk : csq)[(bt * NQ + n) * 32 + i];
    float* Xp = (half ? Kr : Qr) + ((((size_t)(bt * HH + h)) * NQ + n) * DH + i * 2);
    float2 x = *(float2*)Xp;
    float2 o;
    o.x = x.x * cs.x - x.y * cs.y;
    o.y = x.y * cs.x + x.x * cs.y;
    *(float2*)Xp = o;
}

// ---------------------------------------------------------------------------
// Attention: per (b,h,t), flash-style over k tiles of 64, q tiles of 64 rows.
// 256 threads: thread = (row r = tid>>2, quarter g = tid&3) -> 16 score cols,
// 16 output dh cols. Online softmax; distance bias fused.
// ---------------------------------------------------------------------------
__global__ __launch_bounds__(256) void attn_kernel(
    const float* __restrict__ Qr, const float* __restrict__ Kr,
    const float* __restrict__ Vr,
    const float* __restrict__ coords_q, const float* __restrict__ coords_k,
    const uint8_t* __restrict__ qmask, const uint8_t* __restrict__ kmask,
    const float* __restrict__ alpha, float* __restrict__ Y)
{
    __shared__ float Ks[64][68];
    __shared__ float Vs[64][68];
    __shared__ float cqy[64], cqx[64], cky[64], ckx[64];
    __shared__ int qm_s[64], km_s[64];

    const int tid = threadIdx.x;
    int zz = blockIdx.y;                 // [0,128): b*64 + h*4 + t
    const int b = zz >> 6; zz &= 63;
    const int h = zz >> 2; const int t = zz & 3;
    const int bt = b * TT + t;
    const int q0 = blockIdx.x * 64;
    const int r = tid >> 2, g = tid & 3;

    const size_t head_base = ((size_t)(bt * HH + h)) * NQ * DH;
    const float* Qb = Qr + head_base;
    const float* Kb = Kr + head_base;
    const float* Vb = Vr + head_base;

    if (tid < 64) {
        int qi = q0 + tid;
        cqy[tid] = coords_q[(bt * NQ + qi) * 3 + 1];
        cqx[tid] = coords_q[(bt * NQ + qi) * 3 + 2];
        qm_s[tid] = qmask[bt * NQ + qi];
    }

    // Q row into registers (4 threads share a row; L1 handles the redundancy)
    float q_reg[64];
    const float* qrow = Qb + (size_t)(q0 + r) * DH;
#pragma unroll
    for (int d4 = 0; d4 < 16; d4++) {
        float4 v = *(const float4*)(qrow + d4 * 4);
        q_reg[d4*4+0] = v.x; q_reg[d4*4+1] = v.y;
        q_reg[d4*4+2] = v.z; q_reg[d4*4+3] = v.w;
    }
    const float alph = alpha[h];
    float m_run = -INFINITY, l_part = 0.f;
    float acc[16];
#pragma unroll
    for (int j = 0; j < 16; j++) acc[j] = 0.f;

    for (int kt = 0; kt < 9; kt++) {
        const int k0 = kt * 64;
        __syncthreads();   // prev-iter LDS reads done (also covers cq staging)
#pragma unroll
        for (int it = 0; it < 4; it++) {
            int li = tid + it * 256;          // 0..1023
            int lr = li >> 4;
            int lc = (li & 15) * 4;
            *(float4*)&Ks[lr][lc] = *(const float4*)(Kb + (size_t)(k0 + lr) * DH + lc);
            *(float4*)&Vs[lr][lc] = *(const float4*)(Vb + (size_t)(k0 + lr) * DH + lc);
        }
        if (tid < 64) {
            int ki = k0 + tid;
            cky[tid] = coords_k[(bt * NKV + ki) * 3 + 1];
            ckx[tid] = coords_k[(bt * NKV + ki) * 3 + 2];
            km_s[tid] = kmask[bt * NKV + ki];
        }
        __syncthreads();

        const float my_y = cqy[r], my_x = cqx[r];
        const int myqm = qm_s[r];
        float p[16];
        float mloc = -INFINITY;
#pragma unroll
        for (int ci = 0; ci < 16; ci++) {
            const int c = g * 16 + ci;
            float s = 0.f;
#pragma unroll
            for (int d4 = 0; d4 < 16; d4++) {
                float4 kv = *(const float4*)&Ks[c][d4 * 4];
                s += q_reg[d4*4+0] * kv.x;
                s += q_reg[d4*4+1] * kv.y;
                s += q_reg[d4*4+2] * kv.z;
                s += q_reg[d4*4+3] * kv.w;
            }
            // bias — forced-rounded ops to match np's unfused f32 exactly at
            // the dist>0.5 discrete boundary
            float dy = __fsub_rn(my_y, cky[c]);
            float dx = __fsub_rn(my_x, ckx[c]);
            float d2 = __fadd_rn(__fmul_rn(dy, dy), __fmul_rn(dx, dx));
            float dist = __fsqrt_rn(d2);
            float bias = (dist > 0.5f) ? NEGV : 0.f;
            bias += alph * __expf(-10.f * dist);
            if (myqm | km_s[c]) bias = NEGV;
            s = s * 0.125f + bias;     // NEG + finite rounds to NEG: matches ref
            p[ci] = s;
            mloc = fmaxf(mloc, s);
        }
        // group (4-lane) max reduce
        mloc = fmaxf(mloc, __shfl_xor(mloc, 1));
        mloc = fmaxf(mloc, __shfl_xor(mloc, 2));
        float m_new = fmaxf(m_run, mloc);
        float scale = __expf(m_run - m_new);   // first iter: exp(-inf)=0
        float psum = 0.f;
#pragma unroll
        for (int ci = 0; ci < 16; ci++) {
            float pv = __expf(p[ci] - m_new);  // all-NEG row: exp(0)=1 uniform
            p[ci] = pv;
            psum += pv;
        }
        l_part = l_part * scale + psum;
        m_run = m_new;
#pragma unroll
        for (int j = 0; j < 16; j++) acc[j] *= scale;
        // PV: rotate p across the 4-lane group so each thread sees all 64 cols
#pragma unroll
        for (int rot = 0; rot < 4; rot++) {
            const int cg = (g ^ rot) * 16;
#pragma unroll
            for (int ci = 0; ci < 16; ci++) {
                float pp = rot ? __shfl_xor(p[ci], rot) : p[ci];
                const float* vrow = &Vs[cg + ci][g * 16];
                float4 v0 = *(const float4*)(vrow);
                float4 v1 = *(const float4*)(vrow + 4);
                float4 v2 = *(const float4*)(vrow + 8);
                float4 v3 = *(const float4*)(vrow + 12);
                acc[0]  += pp * v0.x; acc[1]  += pp * v0.y; acc[2]  += pp * v0.z; acc[3]  += pp * v0.w;
                acc[4]  += pp * v1.x; acc[5]  += pp * v1.y; acc[6]  += pp * v1.z; acc[7]  += pp * v1.w;
                acc[8]  += pp * v2.x; acc[9]  += pp * v2.y; acc[10] += pp * v2.z; acc[11] += pp * v2.w;
                acc[12] += pp * v3.x; acc[13] += pp * v3.y; acc[14] += pp * v3.z; acc[15] += pp * v3.w;
            }
        }
    }
    // finalize: group-sum of l, divide, store
    float l1 = l_part + __shfl_xor(l_part, 1);
    float l_tot = l1 + __shfl_xor(l1, 2);
    float inv = 1.0f / l_tot;    // l_tot >= 1 always (max entry has p==1)
    float* yrow = Y + ((size_t)(bt * NQ) + q0 + r) * DD + h * DH + g * 16;
#pragma unroll
    for (int j4 = 0; j4 < 4; j4++) {
        float4 o;
        o.x = acc[j4*4+0] * inv; o.y = acc[j4*4+1] * inv;
        o.z = acc[j4*4+2] * inv; o.w = acc[j4*4+3] * inv;
        *(float4*)(yrow + j4 * 4) = o;
    }
}

// ---------------------------------------------------------------------------
extern "C" void kernel_launch(void* const* d_in, const int* in_sizes, int n_in,
                              void* d_out, int out_size, void* d_ws, size_t ws_size,
                              hipStream_t stream)
{
    const float*   q_tokens  = (const float*)d_in[0];
    const float*   kv_tokens = (const float*)d_in[1];
    const float*   coords_q  = (const float*)d_in[2];
    const float*   coords_k  = (const float*)d_in[3];
    const uint8_t* q_pad     = (const uint8_t*)d_in[4];
    const uint8_t* kv_pad    = (const uint8_t*)d_in[5];
    const float*   Wq = (const float*)d_in[6];
    const float*   bq = (const float*)d_in[7];
    const float*   Wk = (const float*)d_in[8];
    const float*   bk = (const float*)d_in[9];
    const float*   Wv = (const float*)d_in[10];
    const float*   bv = (const float*)d_in[11];
    const float*   Wo = (const float*)d_in[12];
    const float*   bo = (const float*)d_in[13];
    const float*   alpha = (const float*)d_in[14];
    const float*   f0 = (const float*)d_in[15];
    const float*   f1 = (const float*)d_in[16];
    const float*   f2 = (const float*)d_in[17];
    float* out = (float*)d_out;

    float* ws = (float*)d_ws;
    const size_t SZ = (size_t)NTOK * DD;     // 4718592
    float* Qr = ws;
    float* Kr = Qr + SZ;
    float* Vr = Kr + SZ;
    float* Yb = Vr + SZ;
    float2* csq = (float2*)(Yb + SZ);        // 147456 float2
    float2* csk = csq + (size_t)NTOK * 32;
    uint8_t* qm_c = (uint8_t*)(csk + (size_t)NTOK * 32);
    uint8_t* km_c = qm_c + NTOK;

    canon_masks_kernel<<<1, 256, 0, stream>>>(q_pad, kv_pad, qm_c, km_c);

    build_cs_kernel<<<(2 * NTOK * 32) / 256, 256, 0, stream>>>(
        coords_q, coords_k, f0, f1, f2, csq, csk);

    dim3 gg(16, 72);
    gemm_xwT_kernel<<<gg, 256, 0, stream>>>(q_tokens,  Wq, bq, Qr, 0);
    gemm_xwT_kernel<<<gg, 256, 0, stream>>>(kv_tokens, Wk, bk, Kr, 0);
    gemm_xwT_kernel<<<gg, 256, 0, stream>>>(kv_tokens, Wv, bv, Vr, 0);

    rope_kernel<<<(2 * BT * HH * NQ * 32) / 256, 256, 0, stream>>>(Qr, Kr, csq, csk);

    attn_kernel<<<dim3(9, BB * HH * TT), 256, 0, stream>>>(
        Qr, Kr, Vr, coords_q, coords_k, qm_c, km_c, alpha, Yb);

    gemm_xwT_kernel<<<gg, 256, 0, stream>>>(Yb, Wo, bo, out, 1);
}

// Round 5
// 651.781 us; speedup vs baseline: 1.7911x; 1.7911x over previous
//
#include <hip/hip_runtime.h>
#include <math.h>
#include <stdint.h>

#define BB 2
#define TT 4
#define NQ 576
#define NKV 576
#define DD 1024
#define HH 16
#define DH 64
#define BT (BB*TT)          // 8
#define NTOK (BT*NQ)        // 4608
#define NEGV (-(3.402823466e38f) * 0.5f)   // == np.finfo(f32).min / 2, exact

typedef __attribute__((ext_vector_type(8))) short short8v;
typedef __attribute__((ext_vector_type(4))) float f32x4;

// round-to-nearest-even fp32 -> bf16 bits
__device__ inline ushort f2bf(float f) {
    union { float f; uint32_t u; } v; v.f = f;
    return (ushort)((v.u + 0x7FFFu + ((v.u >> 16) & 1u)) >> 16);
}

// ---------------------------------------------------------------------------
// Mask canonicalization (unchanged, worked in R3): detects int32-vs-uint8
// bool upload encoding; writes canonical uint8.
// ---------------------------------------------------------------------------
__global__ __launch_bounds__(256) void canon_masks_kernel(
    const uint8_t* __restrict__ qm_raw, const uint8_t* __restrict__ km_raw,
    uint8_t* __restrict__ qm_out, uint8_t* __restrict__ km_out)
{
    __shared__ int flag_s;
    const int tid = threadIdx.x;          // single block of 256
    if (tid == 0) flag_s = 0;
    __syncthreads();
    int local = 0;
    for (int j = tid; j < NTOK; j += 256) {
        if ((j & 3) != 0 && (qm_raw[j] | km_raw[j])) local = 1;
    }
    if (local) atomicOr(&flag_s, 1);
    __syncthreads();
    const int is_u8 = flag_s;             // 1 => raw uint8 bools, 0 => int32
    const int* qi32 = (const int*)qm_raw;
    const int* ki32 = (const int*)km_raw;
    for (int j = tid; j < NTOK; j += 256) {
        qm_out[j] = is_u8 ? qm_raw[j] : (uint8_t)(qi32[j] != 0);
        km_out[j] = is_u8 ? km_raw[j] : (uint8_t)(ki32[j] != 0);
    }
}

// ---------------------------------------------------------------------------
// cos/sin tables (unchanged)
// ---------------------------------------------------------------------------
__global__ __launch_bounds__(256) void build_cs_kernel(
    const float* __restrict__ cq, const float* __restrict__ ck,
    const float* __restrict__ f0, const float* __restrict__ f1,
    const float* __restrict__ f2,
    float2* __restrict__ csq, float2* __restrict__ csk)
{
    const int PER = NTOK * 32;              // 147456
    int idx = blockIdx.x * 256 + threadIdx.x;
    int half = idx / PER;
    int r = idx - half * PER;
    int i = r & 31;
    int tok = r >> 5;
    int axis; float f;
    if (i < 12)      { axis = 0; f = f0[i];      }
    else if (i < 22) { axis = 1; f = f1[i - 12]; }
    else             { axis = 2; f = f2[i - 22]; }
    const float* C = half ? ck : cq;
    float c = C[tok * 3 + axis];
    float arg = __fmul_rn(__fmul_rn(1.57079632679489662f, c), f);
    float s, co;
    __sincosf(arg, &s, &co);
    float2 out; out.x = co; out.y = s;
    (half ? csk : csq)[tok * 32 + i] = out;
}

// ---------------------------------------------------------------------------
// bf16 MFMA GEMM: O[m,n] = sum_k X[m,k]*W[n,k] + b[n]  (M=4608, N=K=1024)
// BM=BN=128, BK=32; 256 threads = 4 waves, each 64x64 out (4x4 16x16 frags).
// fp32 HBM -> bf16 LDS conversion in the staging path. LDS rows padded to 40
// bf16 (20 words): 16 frag rows spread over 8 banks -> 2-way (free).
// mode 0: store to [bt,h,ntok,dh]; mode 1: row-major [m,1024].
// ---------------------------------------------------------------------------
__global__ __launch_bounds__(256) void gemm_mfma_kernel(
    const float* __restrict__ X, const float* __restrict__ W,
    const float* __restrict__ bias, float* __restrict__ O, const int mode)
{
    __shared__ ushort As[128][40];
    __shared__ ushort Bs[128][40];
    const int tid = threadIdx.x;
    const int m0 = blockIdx.y * 128, n0 = blockIdx.x * 128;
    const int lane = tid & 63, w = tid >> 6;
    const int wm = (w >> 1) * 64, wn = (w & 1) * 64;
    const int srow = tid >> 1, scol = (tid & 1) * 16;

    const float* Xp = X + (size_t)(m0 + srow) * DD + scol;
    const float* Wp = W + (size_t)(n0 + srow) * DD + scol;

    f32x4 acc[4][4];
#pragma unroll
    for (int m = 0; m < 4; m++)
#pragma unroll
        for (int n = 0; n < 4; n++) acc[m][n] = (f32x4)0.f;

    const int koff = (lane >> 4) * 8;    // bf16 elem offset within LDS row
    const int frow = lane & 15;

    for (int k0 = 0; k0 < DD; k0 += 32) {
        float4 xa = *(const float4*)(Xp + k0);
        float4 xb = *(const float4*)(Xp + k0 + 4);
        float4 xc = *(const float4*)(Xp + k0 + 8);
        float4 xd = *(const float4*)(Xp + k0 + 12);
        float4 wa = *(const float4*)(Wp + k0);
        float4 wb = *(const float4*)(Wp + k0 + 4);
        float4 wc = *(const float4*)(Wp + k0 + 8);
        float4 wd = *(const float4*)(Wp + k0 + 12);
        __syncthreads();   // previous iteration's frag reads complete
        {
            ushort4 t;
            t.x = f2bf(xa.x); t.y = f2bf(xa.y); t.z = f2bf(xa.z); t.w = f2bf(xa.w);
            *(ushort4*)&As[srow][scol + 0] = t;
            t.x = f2bf(xb.x); t.y = f2bf(xb.y); t.z = f2bf(xb.z); t.w = f2bf(xb.w);
            *(ushort4*)&As[srow][scol + 4] = t;
            t.x = f2bf(xc.x); t.y = f2bf(xc.y); t.z = f2bf(xc.z); t.w = f2bf(xc.w);
            *(ushort4*)&As[srow][scol + 8] = t;
            t.x = f2bf(xd.x); t.y = f2bf(xd.y); t.z = f2bf(xd.z); t.w = f2bf(xd.w);
            *(ushort4*)&As[srow][scol + 12] = t;
            t.x = f2bf(wa.x); t.y = f2bf(wa.y); t.z = f2bf(wa.z); t.w = f2bf(wa.w);
            *(ushort4*)&Bs[srow][scol + 0] = t;
            t.x = f2bf(wb.x); t.y = f2bf(wb.y); t.z = f2bf(wb.z); t.w = f2bf(wb.w);
            *(ushort4*)&Bs[srow][scol + 4] = t;
            t.x = f2bf(wc.x); t.y = f2bf(wc.y); t.z = f2bf(wc.z); t.w = f2bf(wc.w);
            *(ushort4*)&Bs[srow][scol + 8] = t;
            t.x = f2bf(wd.x); t.y = f2bf(wd.y); t.z = f2bf(wd.z); t.w = f2bf(wd.w);
            *(ushort4*)&Bs[srow][scol + 12] = t;
        }
        __syncthreads();
        short8v a[4], b[4];
#pragma unroll
        for (int m = 0; m < 4; m++)
            a[m] = *(const short8v*)&As[wm + m * 16 + frow][koff];
#pragma unroll
        for (int n = 0; n < 4; n++)
            b[n] = *(const short8v*)&Bs[wn + n * 16 + frow][koff];
#pragma unroll
        for (int m = 0; m < 4; m++)
#pragma unroll
            for (int n = 0; n < 4; n++)
                acc[m][n] = __builtin_amdgcn_mfma_f32_16x16x32_bf16(
                    a[m], b[n], acc[m][n], 0, 0, 0);
    }

    // epilogue: C frag mapping col=lane&15, row=(lane>>4)*4+reg  [m89-verified]
#pragma unroll
    for (int m = 0; m < 4; m++) {
        const int gr0 = m0 + wm + m * 16 + (lane >> 4) * 4;
#pragma unroll
        for (int n = 0; n < 4; n++) {
            const int gc = n0 + wn + n * 16 + (lane & 15);
            const float bv_ = bias[gc];
            f32x4 c = acc[m][n];
#pragma unroll
            for (int i = 0; i < 4; i++) {
                const int row = gr0 + i;
                const float val = c[i] + bv_;
                if (mode == 0) {
                    int bt = row / NQ, nn = row - bt * NQ;
                    int h = gc >> 6, dh = gc & 63;
                    O[(((size_t)(bt * HH + h)) * NQ + nn) * DH + dh] = val;
                } else {
                    O[(size_t)row * DD + gc] = val;
                }
            }
        }
    }
}

// ---------------------------------------------------------------------------
// RoPE in place on Qr/Kr (unchanged)
// ---------------------------------------------------------------------------
__global__ __launch_bounds__(256) void rope_kernel(
    float* __restrict__ Qr, float* __restrict__ Kr,
    const float2* __restrict__ csq, const float2* __restrict__ csk)
{
    const int PER = BT * HH * NQ * 32;       // 2359296
    int idx = blockIdx.x * 256 + threadIdx.x;
    int half = idx / PER;
    int r = idx - half * PER;
    int i = r & 31;
    int n = (r >> 5) % NQ;
    int rest = (r >> 5) / NQ;
    int h = rest & (HH - 1);
    int bt = rest >> 4;
    float2 cs = (half ? csk : csq)[(bt * NQ + n) * 32 + i];
    float* Xp = (half ? Kr : Qr) + ((((size_t)(bt * HH + h)) * NQ + n) * DH + i * 2);
    float2 x = *(float2*)Xp;
    float2 o;
    o.x = x.x * cs.x - x.y * cs.y;
    o.y = x.y * cs.x + x.x * cs.y;
    *(float2*)Xp = o;
}

// ---------------------------------------------------------------------------
// Attention (fp32, flash-style) with LDS XOR swizzle on Ks/Vs:
//   physical col = logical col ^ (((row>>4)&3)<<2)
// Spreads the 4 rows {c, c+16, c+32, c+48} active per ds_read_b128 across
// disjoint bank quads -> conflict-free (was 4-way, 1.27e8 conflicts).
// ---------------------------------------------------------------------------
#define SWZ(rr, cc) ((cc) ^ ((((rr) >> 4) & 3) << 2))

__global__ __launch_bounds__(256) void attn_kernel(
    const float* __restrict__ Qr, const float* __restrict__ Kr,
    const float* __restrict__ Vr,
    const float* __restrict__ coords_q, const float* __restrict__ coords_k,
    const uint8_t* __restrict__ qmask, const uint8_t* __restrict__ kmask,
    const float* __restrict__ alpha, float* __restrict__ Y)
{
    __shared__ float Ks[64][68];
    __shared__ float Vs[64][68];
    __shared__ float cqy[64], cqx[64], cky[64], ckx[64];
    __shared__ int qm_s[64], km_s[64];

    const int tid = threadIdx.x;
    int zz = blockIdx.y;                 // [0,128): b*64 + h*4 + t
    const int b = zz >> 6; zz &= 63;
    const int h = zz >> 2; const int t = zz & 3;
    const int bt = b * TT + t;
    const int q0 = blockIdx.x * 64;
    const int r = tid >> 2, g = tid & 3;

    const size_t head_base = ((size_t)(bt * HH + h)) * NQ * DH;
    const float* Qb = Qr + head_base;
    const float* Kb = Kr + head_base;
    const float* Vb = Vr + head_base;

    if (tid < 64) {
        int qi = q0 + tid;
        cqy[tid] = coords_q[(bt * NQ + qi) * 3 + 1];
        cqx[tid] = coords_q[(bt * NQ + qi) * 3 + 2];
        qm_s[tid] = qmask[bt * NQ + qi];
    }

    float q_reg[64];
    const float* qrow = Qb + (size_t)(q0 + r) * DH;
#pragma unroll
    for (int d4 = 0; d4 < 16; d4++) {
        float4 v = *(const float4*)(qrow + d4 * 4);
        q_reg[d4*4+0] = v.x; q_reg[d4*4+1] = v.y;
        q_reg[d4*4+2] = v.z; q_reg[d4*4+3] = v.w;
    }
    const float alph = alpha[h];
    float m_run = -INFINITY, l_part = 0.f;
    float acc[16];
#pragma unroll
    for (int j = 0; j < 16; j++) acc[j] = 0.f;

    for (int kt = 0; kt < 9; kt++) {
        const int k0 = kt * 64;
        __syncthreads();
#pragma unroll
        for (int it = 0; it < 4; it++) {
            int li = tid + it * 256;          // 0..1023
            int lr = li >> 4;
            int lc = (li & 15) * 4;
            int lcs = SWZ(lr, lc);
            *(float4*)&Ks[lr][lcs] = *(const float4*)(Kb + (size_t)(k0 + lr) * DH + lc);
            *(float4*)&Vs[lr][lcs] = *(const float4*)(Vb + (size_t)(k0 + lr) * DH + lc);
        }
        if (tid < 64) {
            int ki = k0 + tid;
            cky[tid] = coords_k[(bt * NKV + ki) * 3 + 1];
            ckx[tid] = coords_k[(bt * NKV + ki) * 3 + 2];
            km_s[tid] = kmask[bt * NKV + ki];
        }
        __syncthreads();

        const float my_y = cqy[r], my_x = cqx[r];
        const int myqm = qm_s[r];
        float p[16];
        float mloc = -INFINITY;
#pragma unroll
        for (int ci = 0; ci < 16; ci++) {
            const int c = g * 16 + ci;
            const int swc = ((c >> 4) & 3) << 2;
            float s = 0.f;
#pragma unroll
            for (int d4 = 0; d4 < 16; d4++) {
                float4 kv = *(const float4*)&Ks[c][(d4 * 4) ^ swc];
                s += q_reg[d4*4+0] * kv.x;
                s += q_reg[d4*4+1] * kv.y;
                s += q_reg[d4*4+2] * kv.z;
                s += q_reg[d4*4+3] * kv.w;
            }
            float dy = __fsub_rn(my_y, cky[c]);
            float dx = __fsub_rn(my_x, ckx[c]);
            float d2 = __fadd_rn(__fmul_rn(dy, dy), __fmul_rn(dx, dx));
            float dist = __fsqrt_rn(d2);
            float bias = (dist > 0.5f) ? NEGV : 0.f;
            bias += alph * __expf(-10.f * dist);
            if (myqm | km_s[c]) bias = NEGV;
            s = s * 0.125f + bias;
            p[ci] = s;
            mloc = fmaxf(mloc, s);
        }
        mloc = fmaxf(mloc, __shfl_xor(mloc, 1));
        mloc = fmaxf(mloc, __shfl_xor(mloc, 2));
        float m_new = fmaxf(m_run, mloc);
        float scale = __expf(m_run - m_new);
        float psum = 0.f;
#pragma unroll
        for (int ci = 0; ci < 16; ci++) {
            float pv = __expf(p[ci] - m_new);
            p[ci] = pv;
            psum += pv;
        }
        l_part = l_part * scale + psum;
        m_run = m_new;
#pragma unroll
        for (int j = 0; j < 16; j++) acc[j] *= scale;
#pragma unroll
        for (int rot = 0; rot < 4; rot++) {
            const int cg = (g ^ rot) * 16;
#pragma unroll
            for (int ci = 0; ci < 16; ci++) {
                const int rowv = cg + ci;
                const int swv = ((rowv >> 4) & 3) << 2;
                float pp = rot ? __shfl_xor(p[ci], rot) : p[ci];
                float4 v0 = *(const float4*)&Vs[rowv][(g * 16 + 0) ^ swv];
                float4 v1 = *(const float4*)&Vs[rowv][(g * 16 + 4) ^ swv];
                float4 v2 = *(const float4*)&Vs[rowv][(g * 16 + 8) ^ swv];
                float4 v3 = *(const float4*)&Vs[rowv][(g * 16 + 12) ^ swv];
                acc[0]  += pp * v0.x; acc[1]  += pp * v0.y; acc[2]  += pp * v0.z; acc[3]  += pp * v0.w;
                acc[4]  += pp * v1.x; acc[5]  += pp * v1.y; acc[6]  += pp * v1.z; acc[7]  += pp * v1.w;
                acc[8]  += pp * v2.x; acc[9]  += pp * v2.y; acc[10] += pp * v2.z; acc[11] += pp * v2.w;
                acc[12] += pp * v3.x; acc[13] += pp * v3.y; acc[14] += pp * v3.z; acc[15] += pp * v3.w;
            }
        }
    }
    float l1 = l_part + __shfl_xor(l_part, 1);
    float l_tot = l1 + __shfl_xor(l1, 2);
    float inv = 1.0f / l_tot;
    float* yrow = Y + ((size_t)(bt * NQ) + q0 + r) * DD + h * DH + g * 16;
#pragma unroll
    for (int j4 = 0; j4 < 4; j4++) {
        float4 o;
        o.x = acc[j4*4+0] * inv; o.y = acc[j4*4+1] * inv;
        o.z = acc[j4*4+2] * inv; o.w = acc[j4*4+3] * inv;
        *(float4*)(yrow + j4 * 4) = o;
    }
}

// ---------------------------------------------------------------------------
extern "C" void kernel_launch(void* const* d_in, const int* in_sizes, int n_in,
                              void* d_out, int out_size, void* d_ws, size_t ws_size,
                              hipStream_t stream)
{
    const float*   q_tokens  = (const float*)d_in[0];
    const float*   kv_tokens = (const float*)d_in[1];
    const float*   coords_q  = (const float*)d_in[2];
    const float*   coords_k  = (const float*)d_in[3];
    const uint8_t* q_pad     = (const uint8_t*)d_in[4];
    const uint8_t* kv_pad    = (const uint8_t*)d_in[5];
    const float*   Wq = (const float*)d_in[6];
    const float*   bq = (const float*)d_in[7];
    const float*   Wk = (const float*)d_in[8];
    const float*   bk = (const float*)d_in[9];
    const float*   Wv = (const float*)d_in[10];
    const float*   bv = (const float*)d_in[11];
    const float*   Wo = (const float*)d_in[12];
    const float*   bo = (const float*)d_in[13];
    const float*   alpha = (const float*)d_in[14];
    const float*   f0 = (const float*)d_in[15];
    const float*   f1 = (const float*)d_in[16];
    const float*   f2 = (const float*)d_in[17];
    float* out = (float*)d_out;

    float* ws = (float*)d_ws;
    const size_t SZ = (size_t)NTOK * DD;     // 4718592
    float* Qr = ws;
    float* Kr = Qr + SZ;
    float* Vr = Kr + SZ;
    float* Yb = Vr + SZ;
    float2* csq = (float2*)(Yb + SZ);        // 147456 float2
    float2* csk = csq + (size_t)NTOK * 32;
    uint8_t* qm_c = (uint8_t*)(csk + (size_t)NTOK * 32);
    uint8_t* km_c = qm_c + NTOK;

    canon_masks_kernel<<<1, 256, 0, stream>>>(q_pad, kv_pad, qm_c, km_c);

    build_cs_kernel<<<(2 * NTOK * 32) / 256, 256, 0, stream>>>(
        coords_q, coords_k, f0, f1, f2, csq, csk);

    dim3 gg(DD / 128, NTOK / 128);           // (8, 36)
    gemm_mfma_kernel<<<gg, 256, 0, stream>>>(q_tokens,  Wq, bq, Qr, 0);
    gemm_mfma_kernel<<<gg, 256, 0, stream>>>(kv_tokens, Wk, bk, Kr, 0);
    gemm_mfma_kernel<<<gg, 256, 0, stream>>>(kv_tokens, Wv, bv, Vr, 0);

    rope_kernel<<<(2 * BT * HH * NQ * 32) / 256, 256, 0, stream>>>(Qr, Kr, csq, csk);

    attn_kernel<<<dim3(9, BB * HH * TT), 256, 0, stream>>>(
        Qr, Kr, Vr, coords_q, coords_k, qm_c, km_c, alpha, Yb);

    gemm_mfma_kernel<<<gg, 256, 0, stream>>>(Yb, Wo, bo, out, 1);
}

// Round 6
// 358.315 us; speedup vs baseline: 3.2581x; 1.8190x over previous
//
#include <hip/hip_runtime.h>
#include <math.h>
#include <stdint.h>

#define BB 2
#define TT 4
#define NQ 576
#define NKV 576
#define DD 1024
#define HH 16
#define DH 64
#define BT (BB*TT)          // 8
#define NTOK (BT*NQ)        // 4608
#define NEGV (-(3.402823466e38f) * 0.5f)   // == np.finfo(f32).min / 2, exact

typedef __attribute__((ext_vector_type(8))) short short8v;
typedef __attribute__((ext_vector_type(4))) float f32x4;

// round-to-nearest-even fp32 -> bf16 bits
__device__ inline ushort f2bf(float f) {
    union { float f; uint32_t u; } v; v.f = f;
    return (ushort)((v.u + 0x7FFFu + ((v.u >> 16) & 1u)) >> 16);
}

// async global->LDS, 16 B per lane; lds dest must be wave-uniform base
__device__ inline void gld_lds16(const ushort* g, ushort* l) {
    __builtin_amdgcn_global_load_lds(
        (const __attribute__((address_space(1))) unsigned int*)g,
        (__attribute__((address_space(3))) unsigned int*)l, 16, 0, 0);
}

// ---------------------------------------------------------------------------
// Mask canonicalization (unchanged; verified R3)
// ---------------------------------------------------------------------------
__global__ __launch_bounds__(256) void canon_masks_kernel(
    const uint8_t* __restrict__ qm_raw, const uint8_t* __restrict__ km_raw,
    uint8_t* __restrict__ qm_out, uint8_t* __restrict__ km_out)
{
    __shared__ int flag_s;
    const int tid = threadIdx.x;
    if (tid == 0) flag_s = 0;
    __syncthreads();
    int local = 0;
    for (int j = tid; j < NTOK; j += 256) {
        if ((j & 3) != 0 && (qm_raw[j] | km_raw[j])) local = 1;
    }
    if (local) atomicOr(&flag_s, 1);
    __syncthreads();
    const int is_u8 = flag_s;
    const int* qi32 = (const int*)qm_raw;
    const int* ki32 = (const int*)km_raw;
    for (int j = tid; j < NTOK; j += 256) {
        qm_out[j] = is_u8 ? qm_raw[j] : (uint8_t)(qi32[j] != 0);
        km_out[j] = is_u8 ? km_raw[j] : (uint8_t)(ki32[j] != 0);
    }
}

// ---------------------------------------------------------------------------
// cos/sin tables (unchanged; verified R3)
// ---------------------------------------------------------------------------
__global__ __launch_bounds__(256) void build_cs_kernel(
    const float* __restrict__ cq, const float* __restrict__ ck,
    const float* __restrict__ f0, const float* __restrict__ f1,
    const float* __restrict__ f2,
    float2* __restrict__ csq, float2* __restrict__ csk)
{
    const int PER = NTOK * 32;
    int idx = blockIdx.x * 256 + threadIdx.x;
    int half = idx / PER;
    int r = idx - half * PER;
    int i = r & 31;
    int tok = r >> 5;
    int axis; float f;
    if (i < 12)      { axis = 0; f = f0[i];      }
    else if (i < 22) { axis = 1; f = f1[i - 12]; }
    else             { axis = 2; f = f2[i - 22]; }
    const float* C = half ? ck : cq;
    float c = C[tok * 3 + axis];
    float arg = __fmul_rn(__fmul_rn(1.57079632679489662f, c), f);
    float s, co;
    __sincosf(arg, &s, &co);
    float2 out; out.x = co; out.y = s;
    (half ? csk : csq)[tok * 32 + i] = out;
}

// ---------------------------------------------------------------------------
// fp32 -> bf16 bulk convert (vectorized, n4 = elems/4)
// ---------------------------------------------------------------------------
__global__ __launch_bounds__(256) void f2bf_kernel(
    const float* __restrict__ src, ushort* __restrict__ dst, int n4)
{
    int i = blockIdx.x * 256 + threadIdx.x;
    if (i < n4) {
        float4 v = ((const float4*)src)[i];
        ushort4 o;
        o.x = f2bf(v.x); o.y = f2bf(v.y); o.z = f2bf(v.z); o.w = f2bf(v.w);
        ((ushort4*)dst)[i] = o;
    }
}

// ---------------------------------------------------------------------------
// bf16 MFMA GEMM, m97 recipe: O[m,n] = sum_k X[m,k]*W[n,k] + b[n]
// BM=BN=128, BK=64; linear LDS [128][64] bf16, global_load_lds width 16.
// mode 0: fp32 scatter [bt,h,ntok,dh]; mode 1: fp32 row-major [m,1024];
// mode 2: bf16 scatter [bt,h,ntok,dh].
// ---------------------------------------------------------------------------
__global__ __launch_bounds__(256) void gemm_bf16_kernel(
    const ushort* __restrict__ X, const ushort* __restrict__ W,
    const float* __restrict__ bias, void* __restrict__ O, const int mode)
{
    __shared__ ushort As[128 * 64];
    __shared__ ushort Bs[128 * 64];
    const int tid = threadIdx.x;
    const int m0 = blockIdx.x * 128, n0 = blockIdx.y * 128;
    const int lane = tid & 63, w = tid >> 6;
    const int wm = (w >> 1) * 64, wn = (w & 1) * 64;
    const int frow = lane & 15, koff = (lane >> 4) * 8;

    f32x4 acc[4][4];
#pragma unroll
    for (int m = 0; m < 4; m++)
#pragma unroll
        for (int n = 0; n < 4; n++) acc[m][n] = (f32x4)0.f;

    // staging geometry: 16 chunks of 1 KiB (8 rows each); wave w owns chunks w*4..w*4+3
    const int srowo = lane >> 3;            // 0..7 within chunk
    const int scole = (lane & 7) * 8;       // elem col

    for (int k0 = 0; k0 < DD; k0 += 64) {
        __syncthreads();   // previous iteration's frag reads complete
#pragma unroll
        for (int c = 0; c < 4; c++) {
            int chunk = w * 4 + c;
            int row = chunk * 8 + srowo;
            gld_lds16(&X[(size_t)(m0 + row) * DD + k0 + scole], &As[chunk * 512]);
            gld_lds16(&W[(size_t)(n0 + row) * DD + k0 + scole], &Bs[chunk * 512]);
        }
        __syncthreads();   // barrier drains vmcnt -> staged data visible
#pragma unroll
        for (int ks = 0; ks < 2; ks++) {
            short8v a[4], b[4];
#pragma unroll
            for (int m = 0; m < 4; m++)
                a[m] = *(const short8v*)&As[(wm + m * 16 + frow) * 64 + ks * 32 + koff];
#pragma unroll
            for (int n = 0; n < 4; n++)
                b[n] = *(const short8v*)&Bs[(wn + n * 16 + frow) * 64 + ks * 32 + koff];
#pragma unroll
            for (int m = 0; m < 4; m++)
#pragma unroll
                for (int n = 0; n < 4; n++)
                    acc[m][n] = __builtin_amdgcn_mfma_f32_16x16x32_bf16(
                        a[m], b[n], acc[m][n], 0, 0, 0);
        }
    }

    // epilogue: C frag mapping col=lane&15, row=(lane>>4)*4+reg [m89-verified]
#pragma unroll
    for (int m = 0; m < 4; m++) {
        const int gr0 = m0 + wm + m * 16 + (lane >> 4) * 4;
#pragma unroll
        for (int n = 0; n < 4; n++) {
            const int gc = n0 + wn + n * 16 + (lane & 15);
            const float bv_ = bias[gc];
            f32x4 c = acc[m][n];
#pragma unroll
            for (int i = 0; i < 4; i++) {
                const int row = gr0 + i;
                const float val = c[i] + bv_;
                if (mode == 1) {
                    ((float*)O)[(size_t)row * DD + gc] = val;
                } else {
                    int bt = row / NQ, nn = row - bt * NQ;
                    int h = gc >> 6, dh = gc & 63;
                    size_t idx = (((size_t)(bt * HH + h)) * NQ + nn) * DH + dh;
                    if (mode == 0) ((float*)O)[idx] = val;
                    else           ((ushort*)O)[idx] = f2bf(val);
                }
            }
        }
    }
}

// ---------------------------------------------------------------------------
// RoPE: reads fp32 Qr/Kr [bt,h,n,64], writes bf16 Qh/Kh same layout
// ---------------------------------------------------------------------------
__global__ __launch_bounds__(256) void rope_kernel(
    const float* __restrict__ Qr, const float* __restrict__ Kr,
    ushort* __restrict__ Qh, ushort* __restrict__ Kh,
    const float2* __restrict__ csq, const float2* __restrict__ csk)
{
    const int PER = BT * HH * NQ * 32;       // 2359296
    int idx = blockIdx.x * 256 + threadIdx.x;
    int half = idx / PER;
    int r = idx - half * PER;
    int i = r & 31;
    int n = (r >> 5) % NQ;
    int rest = (r >> 5) / NQ;
    int h = rest & (HH - 1);
    int bt = rest >> 4;
    float2 cs = (half ? csk : csq)[(bt * NQ + n) * 32 + i];
    size_t off = (((size_t)(bt * HH + h)) * NQ + n) * DH + i * 2;
    float2 x = *(const float2*)((half ? Kr : Qr) + off);
    float ox = x.x * cs.x - x.y * cs.y;
    float oy = x.y * cs.x + x.x * cs.y;
    uint32_t pk = (uint32_t)f2bf(ox) | ((uint32_t)f2bf(oy) << 16);
    *(uint32_t*)((half ? Kh : Qh) + off) = pk;
}

// ---------------------------------------------------------------------------
// MFMA flash attention. Block = 4 waves; wave w owns q-rows [q0+w*16, +16).
// QK: D[kv,q] = mfma(K_frag, Q_frag) over 4 kv-16-tiles x 2 k-steps.
// Softmax online in [kv,q] layout (xor-16/32 reduces; q = lane&15).
// P -> bf16 via pad-72 LDS (per-wave), PV: D2[q,dh] = mfma(P_frag, Vt_frag).
// ---------------------------------------------------------------------------
__global__ __launch_bounds__(256) void attn_mfma_kernel(
    const ushort* __restrict__ Qh, const ushort* __restrict__ Kh,
    const ushort* __restrict__ Vh,
    const float* __restrict__ coords_q, const float* __restrict__ coords_k,
    const uint8_t* __restrict__ qmask, const uint8_t* __restrict__ kmask,
    const float* __restrict__ alpha, ushort* __restrict__ Yh)
{
    __shared__ ushort Ks[64][72];        // [kv][dh]
    __shared__ ushort Vt[64][72];        // [dh][kv]  (transposed)
    __shared__ ushort Ps[4][16][72];     // per-wave [q][kv]
    __shared__ float cky[64], ckx[64];
    __shared__ int   kms[64];

    const int tid = threadIdx.x;
    const int lane = tid & 63, w = tid >> 6;
    const int quad = lane >> 4, l15 = lane & 15;

    int zz = blockIdx.y;                 // [0,128): b*64 + h*4 + t
    const int b = zz >> 6; zz &= 63;
    const int h = zz >> 2; const int t = zz & 3;
    const int bt = b * TT + t;
    const int q0 = blockIdx.x * 64;

    const size_t hb = ((size_t)(bt * HH + h)) * NQ * DH;
    const int qg = q0 + w * 16 + l15;    // this lane's q-column

    // Q fragments for the whole block (B-frag: col=q=l15, k=quad*8+e)
    const ushort* qrow = Qh + hb + (size_t)qg * DH;
    short8v qf0 = *(const short8v*)(qrow + quad * 8);
    short8v qf1 = *(const short8v*)(qrow + 32 + quad * 8);

    const float my_y = coords_q[(bt * NQ + qg) * 3 + 1];
    const float my_x = coords_q[(bt * NQ + qg) * 3 + 2];
    const int   myqm = qmask[bt * NQ + qg];
    const float alph = alpha[h];

    float m_run = -INFINITY, l_run = 0.f;
    f32x4 oacc[4];
#pragma unroll
    for (int i = 0; i < 4; i++) oacc[i] = (f32x4)0.f;

    for (int kt = 0; kt < 9; kt++) {
        const int k0 = kt * 64;
        __syncthreads();   // prev tile's LDS reads complete
        {   // stage K rows (coalesced loads, padded b128 writes)
            int kv = tid >> 2, c = (tid & 3) * 16;
            const ushort* src = Kh + hb + (size_t)(k0 + kv) * DH + c;
            *(short8v*)&Ks[kv][c]     = *(const short8v*)(src);
            *(short8v*)&Ks[kv][c + 8] = *(const short8v*)(src + 8);
        }
        {   // stage V transposed (coalesced loads, conflict-free b16 writes)
            int kv = tid >> 2, dh0 = (tid & 3) * 16;
            const ushort* vsrc = Vh + hb + (size_t)(k0 + kv) * DH + dh0;
            short8v v0 = *(const short8v*)(vsrc);
            short8v v1 = *(const short8v*)(vsrc + 8);
#pragma unroll
            for (int e = 0; e < 8; e++) Vt[dh0 + e][kv] = (ushort)v0[e];
#pragma unroll
            for (int e = 0; e < 8; e++) Vt[dh0 + 8 + e][kv] = (ushort)v1[e];
        }
        if (tid < 64) {
            int ki = k0 + tid;
            cky[tid] = coords_k[(bt * NKV + ki) * 3 + 1];
            ckx[tid] = coords_k[(bt * NKV + ki) * 3 + 2];
            kms[tid] = kmask[bt * NKV + ki];
        }
        __syncthreads();

        // QK^T: D[kv_local, q] per jt tile
        f32x4 sc[4];
#pragma unroll
        for (int jt = 0; jt < 4; jt++) sc[jt] = (f32x4)0.f;
#pragma unroll
        for (int jt = 0; jt < 4; jt++) {
            short8v kf0 = *(const short8v*)&Ks[jt * 16 + l15][quad * 8];
            short8v kf1 = *(const short8v*)&Ks[jt * 16 + l15][32 + quad * 8];
            sc[jt] = __builtin_amdgcn_mfma_f32_16x16x32_bf16(kf0, qf0, sc[jt], 0, 0, 0);
            sc[jt] = __builtin_amdgcn_mfma_f32_16x16x32_bf16(kf1, qf1, sc[jt], 0, 0, 0);
        }

        // bias + online softmax (lane owns q=l15, kv = jt*16 + quad*4 + r)
        float p[16];
        float mloc = -INFINITY;
#pragma unroll
        for (int jt = 0; jt < 4; jt++) {
#pragma unroll
            for (int r = 0; r < 4; r++) {
                const int kv = jt * 16 + quad * 4 + r;
                float s = sc[jt][r] * 0.125f;
                float dy = __fsub_rn(my_y, cky[kv]);
                float dx = __fsub_rn(my_x, ckx[kv]);
                float d2 = __fadd_rn(__fmul_rn(dy, dy), __fmul_rn(dx, dx));
                float dist = __fsqrt_rn(d2);
                float bias = (dist > 0.5f) ? NEGV : 0.f;
                bias += alph * __expf(-10.f * dist);
                if (myqm | kms[kv]) bias = NEGV;
                s += bias;                 // NEG + finite rounds to NEG
                p[jt * 4 + r] = s;
                mloc = fmaxf(mloc, s);
            }
        }
        mloc = fmaxf(mloc, __shfl_xor(mloc, 16));
        mloc = fmaxf(mloc, __shfl_xor(mloc, 32));
        float m_new = fmaxf(m_run, mloc);
        float scale = __expf(m_run - m_new);    // first iter: exp(-inf)=0
        float psum = 0.f;
#pragma unroll
        for (int i = 0; i < 16; i++) {
            float pv = __expf(p[i] - m_new);    // all-NEG row -> 1.0 uniform
            p[i] = pv;
            psum += pv;
        }
        psum += __shfl_xor(psum, 16);
        psum += __shfl_xor(psum, 32);
        l_run = l_run * scale + psum;
        m_run = m_new;

        // rescale O accumulator: factor for q-row quad*4+r
        float sr[4];
#pragma unroll
        for (int r = 0; r < 4; r++) sr[r] = __shfl(scale, quad * 4 + r);
#pragma unroll
        for (int tdh = 0; tdh < 4; tdh++)
#pragma unroll
            for (int r = 0; r < 4; r++) oacc[tdh][r] *= sr[r];

        // P -> LDS bf16 (transpose to [q][kv]; packed u32 writes, ~2-way banks)
#pragma unroll
        for (int jt = 0; jt < 4; jt++) {
#pragma unroll
            for (int rp = 0; rp < 2; rp++) {
                uint32_t pk = (uint32_t)f2bf(p[jt * 4 + 2 * rp]) |
                              ((uint32_t)f2bf(p[jt * 4 + 2 * rp + 1]) << 16);
                *(uint32_t*)&Ps[w][l15][jt * 16 + quad * 4 + 2 * rp] = pk;
            }
        }
        // wave-private RAW through LDS: compiler inserts lgkmcnt wait

        // PV: A = P[q=l15][kv ks*32+quad*8..], B = Vt[dh][kv ...]
        short8v pa0 = *(const short8v*)&Ps[w][l15][quad * 8];
        short8v pa1 = *(const short8v*)&Ps[w][l15][32 + quad * 8];
#pragma unroll
        for (int tdh = 0; tdh < 4; tdh++) {
            short8v vb0 = *(const short8v*)&Vt[tdh * 16 + l15][quad * 8];
            short8v vb1 = *(const short8v*)&Vt[tdh * 16 + l15][32 + quad * 8];
            oacc[tdh] = __builtin_amdgcn_mfma_f32_16x16x32_bf16(pa0, vb0, oacc[tdh], 0, 0, 0);
            oacc[tdh] = __builtin_amdgcn_mfma_f32_16x16x32_bf16(pa1, vb1, oacc[tdh], 0, 0, 0);
        }
    }

    // finalize: 1/l for q=l15, redistribute to q=quad*4+r rows, store bf16
    float linv = 1.0f / l_run;
    float li[4];
#pragma unroll
    for (int r = 0; r < 4; r++) li[r] = __shfl(linv, quad * 4 + r);
#pragma unroll
    for (int tdh = 0; tdh < 4; tdh++) {
#pragma unroll
        for (int r = 0; r < 4; r++) {
            int tok = bt * NQ + q0 + w * 16 + quad * 4 + r;
            Yh[(size_t)tok * DD + h * DH + tdh * 16 + l15] = f2bf(oacc[tdh][r] * li[r]);
        }
    }
}

// ---------------------------------------------------------------------------
extern "C" void kernel_launch(void* const* d_in, const int* in_sizes, int n_in,
                              void* d_out, int out_size, void* d_ws, size_t ws_size,
                              hipStream_t stream)
{
    const float*   q_tokens  = (const float*)d_in[0];
    const float*   kv_tokens = (const float*)d_in[1];
    const float*   coords_q  = (const float*)d_in[2];
    const float*   coords_k  = (const float*)d_in[3];
    const uint8_t* q_pad     = (const uint8_t*)d_in[4];
    const uint8_t* kv_pad    = (const uint8_t*)d_in[5];
    const float*   Wq = (const float*)d_in[6];
    const float*   bq = (const float*)d_in[7];
    const float*   Wk = (const float*)d_in[8];
    const float*   bk = (const float*)d_in[9];
    const float*   Wv = (const float*)d_in[10];
    const float*   bv = (const float*)d_in[11];
    const float*   Wo = (const float*)d_in[12];
    const float*   bo = (const float*)d_in[13];
    const float*   alpha = (const float*)d_in[14];
    const float*   f0 = (const float*)d_in[15];
    const float*   f1 = (const float*)d_in[16];
    const float*   f2 = (const float*)d_in[17];
    float* out = (float*)d_out;

    const size_t SZ = (size_t)NTOK * DD;     // 4718592
    const size_t WSZ = (size_t)DD * DD;      // 1048576
    float*   Qr  = (float*)d_ws;
    float*   Kr  = Qr + SZ;
    float2*  csq = (float2*)(Kr + SZ);
    float2*  csk = csq + (size_t)NTOK * 32;
    ushort*  qtb = (ushort*)(csk + (size_t)NTOK * 32);
    ushort*  ktb = qtb + SZ;
    ushort*  Wqb = ktb + SZ;
    ushort*  Wkb = Wqb + WSZ;
    ushort*  Wvb = Wkb + WSZ;
    ushort*  Wob = Wvb + WSZ;
    ushort*  Qh  = Wob + WSZ;
    ushort*  Kh  = Qh + SZ;
    ushort*  Vh  = Kh + SZ;
    ushort*  Yh  = Vh + SZ;
    uint8_t* qm_c = (uint8_t*)(Yh + SZ);
    uint8_t* km_c = qm_c + NTOK;

    canon_masks_kernel<<<1, 256, 0, stream>>>(q_pad, kv_pad, qm_c, km_c);

    build_cs_kernel<<<(2 * NTOK * 32) / 256, 256, 0, stream>>>(
        coords_q, coords_k, f0, f1, f2, csq, csk);

    f2bf_kernel<<<(int)(SZ / 4 / 256), 256, 0, stream>>>(q_tokens,  qtb, (int)(SZ / 4));
    f2bf_kernel<<<(int)(SZ / 4 / 256), 256, 0, stream>>>(kv_tokens, ktb, (int)(SZ / 4));
    f2bf_kernel<<<(int)(WSZ / 4 / 256), 256, 0, stream>>>(Wq, Wqb, (int)(WSZ / 4));
    f2bf_kernel<<<(int)(WSZ / 4 / 256), 256, 0, stream>>>(Wk, Wkb, (int)(WSZ / 4));
    f2bf_kernel<<<(int)(WSZ / 4 / 256), 256, 0, stream>>>(Wv, Wvb, (int)(WSZ / 4));
    f2bf_kernel<<<(int)(WSZ / 4 / 256), 256, 0, stream>>>(Wo, Wob, (int)(WSZ / 4));

    dim3 gg(NTOK / 128, DD / 128);           // (36, 8)
    gemm_bf16_kernel<<<gg, 256, 0, stream>>>(qtb, Wqb, bq, Qr, 0);
    gemm_bf16_kernel<<<gg, 256, 0, stream>>>(ktb, Wkb, bk, Kr, 0);
    gemm_bf16_kernel<<<gg, 256, 0, stream>>>(ktb, Wvb, bv, Vh, 2);

    rope_kernel<<<(2 * BT * HH * NQ * 32) / 256, 256, 0, stream>>>(
        Qr, Kr, Qh, Kh, csq, csk);

    attn_mfma_kernel<<<dim3(9, BB * HH * TT), 256, 0, stream>>>(
        Qh, Kh, Vh, coords_q, coords_k, qm_c, km_c, alpha, Yh);

    gemm_bf16_kernel<<<gg, 256, 0, stream>>>(Yh, Wob, bo, out, 1);
}

// Round 7
// 311.935 us; speedup vs baseline: 3.7425x; 1.1487x over previous
//
#include <hip/hip_runtime.h>
#include <math.h>
#include <stdint.h>

#define BB 2
#define TT 4
#define NQ 576
#define NKV 576
#define DD 1024
#define HH 16
#define DH 64
#define BT (BB*TT)          // 8
#define NTOK (BT*NQ)        // 4608
#define NPAIR ((size_t)BT*NQ*NKV)   // 2654208
#define NEGV (-(3.402823466e38f) * 0.5f)   // == np.finfo(f32).min / 2, exact

typedef __attribute__((ext_vector_type(8))) short short8v;
typedef __attribute__((ext_vector_type(4))) float f32x4;

// round-to-nearest-even fp32 -> bf16 bits
__device__ inline ushort f2bf(float f) {
    union { float f; uint32_t u; } v; v.f = f;
    return (ushort)((v.u + 0x7FFFu + ((v.u >> 16) & 1u)) >> 16);
}

// async global->LDS, 16 B per lane; lds dest wave-uniform base + lane*16
__device__ inline void gld_lds16(const ushort* g, ushort* l) {
    __builtin_amdgcn_global_load_lds(
        (const __attribute__((address_space(1))) unsigned int*)g,
        (__attribute__((address_space(3))) unsigned int*)l, 16, 0, 0);
}

// ---------------------------------------------------------------------------
// Mask canonicalization (verified R3): int32-vs-uint8 bool upload detection
// ---------------------------------------------------------------------------
__global__ __launch_bounds__(256) void canon_masks_kernel(
    const uint8_t* __restrict__ qm_raw, const uint8_t* __restrict__ km_raw,
    uint8_t* __restrict__ qm_out, uint8_t* __restrict__ km_out)
{
    __shared__ int flag_s;
    const int tid = threadIdx.x;
    if (tid == 0) flag_s = 0;
    __syncthreads();
    int local = 0;
    for (int j = tid; j < NTOK; j += 256) {
        if ((j & 3) != 0 && (qm_raw[j] | km_raw[j])) local = 1;
    }
    if (local) atomicOr(&flag_s, 1);
    __syncthreads();
    const int is_u8 = flag_s;
    const int* qi32 = (const int*)qm_raw;
    const int* ki32 = (const int*)km_raw;
    for (int j = tid; j < NTOK; j += 256) {
        qm_out[j] = is_u8 ? qm_raw[j] : (uint8_t)(qi32[j] != 0);
        km_out[j] = is_u8 ? km_raw[j] : (uint8_t)(ki32[j] != 0);
    }
}

// ---------------------------------------------------------------------------
// cos/sin tables (verified R3)
// ---------------------------------------------------------------------------
__global__ __launch_bounds__(256) void build_cs_kernel(
    const float* __restrict__ cq, const float* __restrict__ ck,
    const float* __restrict__ f0, const float* __restrict__ f1,
    const float* __restrict__ f2,
    float2* __restrict__ csq, float2* __restrict__ csk)
{
    const int PER = NTOK * 32;
    int idx = blockIdx.x * 256 + threadIdx.x;
    int half = idx / PER;
    int r = idx - half * PER;
    int i = r & 31;
    int tok = r >> 5;
    int axis; float f;
    if (i < 12)      { axis = 0; f = f0[i];      }
    else if (i < 22) { axis = 1; f = f1[i - 12]; }
    else             { axis = 2; f = f2[i - 22]; }
    const float* C = half ? ck : cq;
    float c = C[tok * 3 + axis];
    float arg = __fmul_rn(__fmul_rn(1.57079632679489662f, c), f);
    float s, co;
    __sincosf(arg, &s, &co);
    float2 out; out.x = co; out.y = s;
    (half ? csk : csq)[tok * 32 + i] = out;
}

// ---------------------------------------------------------------------------
// Per-(bt,q,kv) bias precompute: prior = exp(-10*dist) f32; flag = cutoff|pad.
// Shared by all 16 heads (was recomputed per head = 16x redundant VALU).
// Forced-rounding ops keep the dist>0.5 boundary bit-exact vs np.
// ---------------------------------------------------------------------------
__global__ __launch_bounds__(576) void prior_kernel(
    const float* __restrict__ cq, const float* __restrict__ ck,
    const uint8_t* __restrict__ qm, const uint8_t* __restrict__ km,
    float* __restrict__ prior, uint8_t* __restrict__ flagb)
{
    const int bq = blockIdx.x;           // bt*576 + q
    const int kv = threadIdx.x;          // 0..575
    const int bt = bq / NQ;
    const float qy = cq[bq * 3 + 1], qx = cq[bq * 3 + 2];
    const int kb = bt * NKV + kv;
    const float ky = ck[kb * 3 + 1], kx = ck[kb * 3 + 2];
    float dy = __fsub_rn(qy, ky);
    float dx = __fsub_rn(qx, kx);
    float d2 = __fadd_rn(__fmul_rn(dy, dy), __fmul_rn(dx, dx));
    float dist = __fsqrt_rn(d2);
    int fl = (dist > 0.5f) | qm[bq] | km[kb];
    size_t o = (size_t)bq * NKV + kv;
    prior[o] = __expf(-10.f * dist);
    flagb[o] = (uint8_t)fl;
}

// ---------------------------------------------------------------------------
// fp32 -> bf16 bulk convert
// ---------------------------------------------------------------------------
__global__ __launch_bounds__(256) void f2bf_kernel(
    const float* __restrict__ src, ushort* __restrict__ dst, int n4)
{
    int i = blockIdx.x * 256 + threadIdx.x;
    if (i < n4) {
        float4 v = ((const float4*)src)[i];
        ushort4 o;
        o.x = f2bf(v.x); o.y = f2bf(v.y); o.z = f2bf(v.z); o.w = f2bf(v.w);
        ((ushort4*)dst)[i] = o;
    }
}

// ---------------------------------------------------------------------------
// bf16 MFMA GEMM: O[m,n] = sum_k X[m,k]*W[n,k] + b[n]   (M=4608, N=K=1024)
// BM=64, BN=128, BK=64; 576 blocks (2.25/CU); bid&7 = n-tile (XCD-aligned:
// each XCD keeps one 2MB B panel L2-resident). LDS linear + T2 slot-swizzle:
// LDS[row][slot] holds global slot (slot ^ (row&7)); reads XOR back -> b128
// conflict-free (8 lanes/slot * 8 slots = 8-sweep minimum).
// modes: 1 = fp32 row-major [m][1024] (out-proj)
//        3 = bf16 transposed [bt,h,dh,tok] (V)
//        4 = rope+bf16 scatter [bt,h,tok,dh] (Q; cst=csq)
//        5 = same for K (cst=csk)
// ---------------------------------------------------------------------------
__global__ __launch_bounds__(256) void gemm_bf16_kernel(
    const ushort* __restrict__ X, const ushort* __restrict__ W,
    const float* __restrict__ bias, void* __restrict__ O,
    const float2* __restrict__ cst, const int mode)
{
    __shared__ ushort As[64 * 64];
    __shared__ ushort Bs[128 * 64];
    const int tid = threadIdx.x;
    const int bid = blockIdx.x;
    const int m0 = (bid >> 3) * 64, n0 = (bid & 7) * 128;
    const int lane = tid & 63, w = tid >> 6;
    const int wm = (w & 1) * 32, wn = (w >> 1) * 64;
    const int frow = lane & 15, quad = lane >> 4;
    // staging: chunk = 8 rows; lane l -> row c*8 + (l>>3), LDS linear slot l&7;
    // source column slot pre-swizzled so LDS[row][s] = global[row][s ^ (row&7)]
    const int srow = lane >> 3;
    const int scole = ((lane & 7) ^ srow) << 3;    // ushort offset in row

    f32x4 acc[2][4];
#pragma unroll
    for (int m = 0; m < 2; m++)
#pragma unroll
        for (int n = 0; n < 4; n++) acc[m][n] = (f32x4)0.f;

    for (int k0 = 0; k0 < DD; k0 += 64) {
        __syncthreads();
#pragma unroll
        for (int j = 0; j < 2; j++) {
            int c = w * 2 + j;
            gld_lds16(&X[(size_t)(m0 + c * 8 + srow) * DD + k0 + scole], &As[c * 512]);
        }
#pragma unroll
        for (int j = 0; j < 4; j++) {
            int c = w * 4 + j;
            gld_lds16(&W[(size_t)(n0 + c * 8 + srow) * DD + k0 + scole], &Bs[c * 512]);
        }
        __syncthreads();   // implicit vmcnt(0) drain makes staged data visible
        const int rsw = (frow & 7) << 3;
#pragma unroll
        for (int ks = 0; ks < 2; ks++) {
            short8v a[2], b[4];
#pragma unroll
            for (int m = 0; m < 2; m++)
                a[m] = *(const short8v*)&As[(wm + m * 16 + frow) * 64 + ((ks * 32 + quad * 8) ^ rsw)];
#pragma unroll
            for (int n = 0; n < 4; n++)
                b[n] = *(const short8v*)&Bs[(wn + n * 16 + frow) * 64 + ((ks * 32 + quad * 8) ^ rsw)];
#pragma unroll
            for (int m = 0; m < 2; m++)
#pragma unroll
                for (int n = 0; n < 4; n++)
                    acc[m][n] = __builtin_amdgcn_mfma_f32_16x16x32_bf16(
                        a[m], b[n], acc[m][n], 0, 0, 0);
        }
    }

    // epilogue: C frag mapping col=lane&15, row=(lane>>4)*4+reg [m89-verified]
#pragma unroll
    for (int m = 0; m < 2; m++) {
        const int gr0 = m0 + wm + m * 16 + quad * 4;
#pragma unroll
        for (int n = 0; n < 4; n++) {
            const int gc = n0 + wn + n * 16 + frow;
            const float bv_ = bias[gc];
            f32x4 c = acc[m][n];
            if (mode == 1) {
#pragma unroll
                for (int i = 0; i < 4; i++)
                    ((float*)O)[(size_t)(gr0 + i) * DD + gc] = c[i] + bv_;
            } else if (mode == 3) {
                // V transposed: [bt][h][dh][tok]; 4 consecutive toks -> ushort4
                int bt = gr0 / NQ, nn0 = gr0 - bt * NQ;
                int h = gc >> 6, dh = gc & 63;
                ushort4 o4;
                o4.x = f2bf(c[0] + bv_); o4.y = f2bf(c[1] + bv_);
                o4.z = f2bf(c[2] + bv_); o4.w = f2bf(c[3] + bv_);
                *(ushort4*)&((ushort*)O)[(((size_t)(bt * HH + h)) * DH + dh) * NQ + nn0] = o4;
            } else {
                // rope fused: pair partner is adjacent lane (gc^1)
                int h = gc >> 6, dh = gc & 63;
                int i2 = dh >> 1;
#pragma unroll
                for (int i = 0; i < 4; i++) {
                    int tok = gr0 + i;
                    float v = c[i] + bv_;
                    float vp = __shfl_xor(v, 1);
                    float2 cs = cst[tok * 32 + i2];
                    float o = (gc & 1) ? (v * cs.x + vp * cs.y)
                                       : (v * cs.x - vp * cs.y);
                    int bt = tok / NQ, nn = tok - bt * NQ;
                    ((ushort*)O)[(((size_t)(bt * HH + h)) * NQ + nn) * DH + dh] = f2bf(o);
                }
            }
        }
    }
}

// ---------------------------------------------------------------------------
// MFMA flash attention. Wave w owns q-rows [q0+w*16,+16). Bias from
// precomputed prior/flag (shared across heads). V staged from transposed
// global -> conflict-free b128 staging (was 8-way scalar-write transpose).
// ---------------------------------------------------------------------------
__global__ __launch_bounds__(256) void attn_mfma_kernel(
    const ushort* __restrict__ Qh, const ushort* __restrict__ Kh,
    const ushort* __restrict__ Vtg,
    const float* __restrict__ prior, const uint8_t* __restrict__ flagb,
    const float* __restrict__ alpha, ushort* __restrict__ Yh)
{
    __shared__ ushort Ks[64][72];        // [kv][dh]
    __shared__ ushort Vt[64][72];        // [dh][kv]
    __shared__ ushort Ps[4][16][88];     // per-wave [q][kv], pad-88: 2-way writes

    const int tid = threadIdx.x;
    const int lane = tid & 63, w = tid >> 6;
    const int quad = lane >> 4, l15 = lane & 15;

    int zz = blockIdx.y;                 // [0,128): b*64 + h*4 + t
    const int b = zz >> 6; zz &= 63;
    const int h = zz >> 2; const int t = zz & 3;
    const int bt = b * TT + t;
    const int q0 = blockIdx.x * 64;

    const size_t hb = ((size_t)(bt * HH + h)) * NQ * DH;
    const size_t vb = ((size_t)(bt * HH + h)) * DH * NQ;   // transposed base
    const int qg = q0 + w * 16 + l15;

    const ushort* qrow = Qh + hb + (size_t)qg * DH;
    short8v qf0 = *(const short8v*)(qrow + quad * 8);
    short8v qf1 = *(const short8v*)(qrow + 32 + quad * 8);

    const float alph = alpha[h];
    const size_t pbase = ((size_t)(bt * NQ + qg)) * NKV;

    float m_run = -INFINITY, l_run = 0.f;
    f32x4 oacc[4];
#pragma unroll
    for (int i = 0; i < 4; i++) oacc[i] = (f32x4)0.f;

    for (int kt = 0; kt < 9; kt++) {
        const int k0 = kt * 64;
        __syncthreads();
        {   // stage K rows [kv][dh]
            int kv = tid >> 2, c = (tid & 3) * 16;
            const ushort* src = Kh + hb + (size_t)(k0 + kv) * DH + c;
            *(short8v*)&Ks[kv][c]     = *(const short8v*)(src);
            *(short8v*)&Ks[kv][c + 8] = *(const short8v*)(src + 8);
        }
        {   // stage Vt rows [dh][kv] from transposed global (same clean pattern)
            int dh = tid >> 2, c = (tid & 3) * 16;
            const ushort* src = Vtg + vb + (size_t)dh * NQ + k0 + c;
            *(short8v*)&Vt[dh][c]     = *(const short8v*)(src);
            *(short8v*)&Vt[dh][c + 8] = *(const short8v*)(src + 8);
        }
        __syncthreads();

        // QK^T: D[kv_local, q]
        f32x4 sc[4];
#pragma unroll
        for (int jt = 0; jt < 4; jt++) sc[jt] = (f32x4)0.f;
#pragma unroll
        for (int jt = 0; jt < 4; jt++) {
            short8v kf0 = *(const short8v*)&Ks[jt * 16 + l15][quad * 8];
            short8v kf1 = *(const short8v*)&Ks[jt * 16 + l15][32 + quad * 8];
            sc[jt] = __builtin_amdgcn_mfma_f32_16x16x32_bf16(kf0, qf0, sc[jt], 0, 0, 0);
            sc[jt] = __builtin_amdgcn_mfma_f32_16x16x32_bf16(kf1, qf1, sc[jt], 0, 0, 0);
        }

        // bias (precomputed prior/flag) + online softmax
        float p[16];
        float mloc = -INFINITY;
#pragma unroll
        for (int jt = 0; jt < 4; jt++) {
            const size_t po = pbase + k0 + jt * 16 + quad * 4;
            float4 pr = *(const float4*)&prior[po];
            uchar4 fv = *(const uchar4*)&flagb[po];
#pragma unroll
            for (int r = 0; r < 4; r++) {
                float prv = (r == 0) ? pr.x : (r == 1) ? pr.y : (r == 2) ? pr.z : pr.w;
                uint8_t fl = (r == 0) ? fv.x : (r == 1) ? fv.y : (r == 2) ? fv.z : fv.w;
                float s = sc[jt][r] * 0.125f + (fl ? NEGV : alph * prv);
                p[jt * 4 + r] = s;
                mloc = fmaxf(mloc, s);
            }
        }
        mloc = fmaxf(mloc, __shfl_xor(mloc, 16));
        mloc = fmaxf(mloc, __shfl_xor(mloc, 32));
        float m_new = fmaxf(m_run, mloc);
        float scale = __expf(m_run - m_new);    // first iter: exp(-inf)=0
        float psum = 0.f;
#pragma unroll
        for (int i = 0; i < 16; i++) {
            float pv = __expf(p[i] - m_new);    // all-NEG row -> uniform
            p[i] = pv;
            psum += pv;
        }
        psum += __shfl_xor(psum, 16);
        psum += __shfl_xor(psum, 32);
        l_run = l_run * scale + psum;
        m_run = m_new;

        float sr[4];
#pragma unroll
        for (int r = 0; r < 4; r++) sr[r] = __shfl(scale, quad * 4 + r);
#pragma unroll
        for (int tdh = 0; tdh < 4; tdh++)
#pragma unroll
            for (int r = 0; r < 4; r++) oacc[tdh][r] *= sr[r];

        // P -> LDS bf16 transpose to [q][kv]
#pragma unroll
        for (int jt = 0; jt < 4; jt++) {
#pragma unroll
            for (int rp = 0; rp < 2; rp++) {
                uint32_t pk = (uint32_t)f2bf(p[jt * 4 + 2 * rp]) |
                              ((uint32_t)f2bf(p[jt * 4 + 2 * rp + 1]) << 16);
                *(uint32_t*)&Ps[w][l15][jt * 16 + quad * 4 + 2 * rp] = pk;
            }
        }
        // wave-private RAW through LDS: compiler inserts lgkmcnt wait

        short8v pa0 = *(const short8v*)&Ps[w][l15][quad * 8];
        short8v pa1 = *(const short8v*)&Ps[w][l15][32 + quad * 8];
#pragma unroll
        for (int tdh = 0; tdh < 4; tdh++) {
            short8v vb0 = *(const short8v*)&Vt[tdh * 16 + l15][quad * 8];
            short8v vb1 = *(const short8v*)&Vt[tdh * 16 + l15][32 + quad * 8];
            oacc[tdh] = __builtin_amdgcn_mfma_f32_16x16x32_bf16(pa0, vb0, oacc[tdh], 0, 0, 0);
            oacc[tdh] = __builtin_amdgcn_mfma_f32_16x16x32_bf16(pa1, vb1, oacc[tdh], 0, 0, 0);
        }
    }

    float linv = 1.0f / l_run;
    float li[4];
#pragma unroll
    for (int r = 0; r < 4; r++) li[r] = __shfl(linv, quad * 4 + r);
#pragma unroll
    for (int tdh = 0; tdh < 4; tdh++) {
#pragma unroll
        for (int r = 0; r < 4; r++) {
            int tok = bt * NQ + q0 + w * 16 + quad * 4 + r;
            Yh[(size_t)tok * DD + h * DH + tdh * 16 + l15] = f2bf(oacc[tdh][r] * li[r]);
        }
    }
}

// ---------------------------------------------------------------------------
extern "C" void kernel_launch(void* const* d_in, const int* in_sizes, int n_in,
                              void* d_out, int out_size, void* d_ws, size_t ws_size,
                              hipStream_t stream)
{
    const float*   q_tokens  = (const float*)d_in[0];
    const float*   kv_tokens = (const float*)d_in[1];
    const float*   coords_q  = (const float*)d_in[2];
    const float*   coords_k  = (const float*)d_in[3];
    const uint8_t* q_pad     = (const uint8_t*)d_in[4];
    const uint8_t* kv_pad    = (const uint8_t*)d_in[5];
    const float*   Wq = (const float*)d_in[6];
    const float*   bq = (const float*)d_in[7];
    const float*   Wk = (const float*)d_in[8];
    const float*   bk = (const float*)d_in[9];
    const float*   Wv = (const float*)d_in[10];
    const float*   bv = (const float*)d_in[11];
    const float*   Wo = (const float*)d_in[12];
    const float*   bo = (const float*)d_in[13];
    const float*   alpha = (const float*)d_in[14];
    const float*   f0 = (const float*)d_in[15];
    const float*   f1 = (const float*)d_in[16];
    const float*   f2 = (const float*)d_in[17];
    float* out = (float*)d_out;

    const size_t SZ = (size_t)NTOK * DD;     // 4718592
    const size_t WSZ = (size_t)DD * DD;      // 1048576
    float2*  csq  = (float2*)d_ws;
    float2*  csk  = csq + (size_t)NTOK * 32;
    float*   prior = (float*)(csk + (size_t)NTOK * 32);
    ushort*  qtb  = (ushort*)(prior + NPAIR);
    ushort*  ktb  = qtb + SZ;
    ushort*  Wqb  = ktb + SZ;
    ushort*  Wkb  = Wqb + WSZ;
    ushort*  Wvb  = Wkb + WSZ;
    ushort*  Wob  = Wvb + WSZ;
    ushort*  Qh   = Wob + WSZ;
    ushort*  Kh   = Qh + SZ;
    ushort*  Vtg  = Kh + SZ;
    ushort*  Yh   = Vtg + SZ;
    uint8_t* flagb = (uint8_t*)(Yh + SZ);
    uint8_t* qm_c = flagb + NPAIR;
    uint8_t* km_c = qm_c + NTOK;

    canon_masks_kernel<<<1, 256, 0, stream>>>(q_pad, kv_pad, qm_c, km_c);

    build_cs_kernel<<<(2 * NTOK * 32) / 256, 256, 0, stream>>>(
        coords_q, coords_k, f0, f1, f2, csq, csk);

    prior_kernel<<<NTOK, 576, 0, stream>>>(
        coords_q, coords_k, qm_c, km_c, prior, flagb);

    f2bf_kernel<<<(int)(SZ / 4 / 256), 256, 0, stream>>>(q_tokens,  qtb, (int)(SZ / 4));
    f2bf_kernel<<<(int)(SZ / 4 / 256), 256, 0, stream>>>(kv_tokens, ktb, (int)(SZ / 4));
    f2bf_kernel<<<(int)(WSZ / 4 / 256), 256, 0, stream>>>(Wq, Wqb, (int)(WSZ / 4));
    f2bf_kernel<<<(int)(WSZ / 4 / 256), 256, 0, stream>>>(Wk, Wkb, (int)(WSZ / 4));
    f2bf_kernel<<<(int)(WSZ / 4 / 256), 256, 0, stream>>>(Wv, Wvb, (int)(WSZ / 4));
    f2bf_kernel<<<(int)(WSZ / 4 / 256), 256, 0, stream>>>(Wo, Wob, (int)(WSZ / 4));

    const int NBLK = (NTOK / 64) * (DD / 128);   // 72*8 = 576
    gemm_bf16_kernel<<<NBLK, 256, 0, stream>>>(qtb, Wqb, bq, Qh,  csq, 4);
    gemm_bf16_kernel<<<NBLK, 256, 0, stream>>>(ktb, Wkb, bk, Kh,  csk, 5);
    gemm_bf16_kernel<<<NBLK, 256, 0, stream>>>(ktb, Wvb, bv, Vtg, nullptr, 3);

    attn_mfma_kernel<<<dim3(9, BB * HH * TT), 256, 0, stream>>>(
        Qh, Kh, Vtg, prior, flagb, alpha, Yh);

    gemm_bf16_kernel<<<NBLK, 256, 0, stream>>>(Yh, Wob, bo, out, nullptr, 1);
}

// Round 8
// 259.146 us; speedup vs baseline: 4.5049x; 1.2037x over previous
//
#include <hip/hip_runtime.h>
#include <math.h>
#include <stdint.h>

#define BB 2
#define TT 4
#define NQ 576
#define NKV 576
#define DD 1024
#define HH 16
#define DH 64
#define BT (BB*TT)          // 8
#define NTOK (BT*NQ)        // 4608
#define NPAIR ((size_t)BT*NQ*NKV)   // 2654208
#define NEGV (-(3.402823466e38f) * 0.5f)   // == np.finfo(f32).min / 2, exact

typedef __attribute__((ext_vector_type(8))) short short8v;
typedef __attribute__((ext_vector_type(4))) float f32x4;

__device__ inline ushort f2bf(float f) {
    union { float f; uint32_t u; } v; v.f = f;
    return (ushort)((v.u + 0x7FFFu + ((v.u >> 16) & 1u)) >> 16);
}

__device__ inline void gld_lds16(const ushort* g, ushort* l) {
    __builtin_amdgcn_global_load_lds(
        (const __attribute__((address_space(1))) unsigned int*)g,
        (__attribute__((address_space(3))) unsigned int*)l, 16, 0, 0);
}

// ---------------------------------------------------------------------------
// cos/sin tables (verified R3)
// ---------------------------------------------------------------------------
__global__ __launch_bounds__(256) void build_cs_kernel(
    const float* __restrict__ cq, const float* __restrict__ ck,
    const float* __restrict__ f0, const float* __restrict__ f1,
    const float* __restrict__ f2,
    float2* __restrict__ csq, float2* __restrict__ csk)
{
    const int PER = NTOK * 32;
    int idx = blockIdx.x * 256 + threadIdx.x;
    int half = idx / PER;
    int r = idx - half * PER;
    int i = r & 31;
    int tok = r >> 5;
    int axis; float f;
    if (i < 12)      { axis = 0; f = f0[i];      }
    else if (i < 22) { axis = 1; f = f1[i - 12]; }
    else             { axis = 2; f = f2[i - 22]; }
    const float* C = half ? ck : cq;
    float c = C[tok * 3 + axis];
    float arg = __fmul_rn(__fmul_rn(1.57079632679489662f, c), f);
    float s, co;
    __sincosf(arg, &s, &co);
    float2 out; out.x = co; out.y = s;
    (half ? csk : csq)[tok * 32 + i] = out;
}

// ---------------------------------------------------------------------------
// Per-(bt,q,kv) prior/flag precompute, with mask-encoding detection folded in
// (per-block re-detection of int32-vs-uint8 bool upload; scan is L2-hot).
// ---------------------------------------------------------------------------
__global__ __launch_bounds__(576) void prior_kernel(
    const float* __restrict__ cq, const float* __restrict__ ck,
    const uint8_t* __restrict__ qm_raw, const uint8_t* __restrict__ km_raw,
    float* __restrict__ prior, uint8_t* __restrict__ flagb)
{
    __shared__ int flag_s;
    const int tid = threadIdx.x;
    if (tid == 0) flag_s = 0;
    __syncthreads();
    int local = 0;
    for (int j = tid; j < NTOK; j += 576) {
        if ((j & 3) != 0 && (qm_raw[j] | km_raw[j])) local = 1;
    }
    if (local) atomicOr(&flag_s, 1);
    __syncthreads();
    const int is_u8 = flag_s;

    const int bq = blockIdx.x;           // bt*576 + q
    const int kv = tid;                  // 0..575
    const int bt = bq / NQ;
    const int kb = bt * NKV + kv;
    uint8_t qmv = is_u8 ? qm_raw[bq] : (uint8_t)(((const int*)qm_raw)[bq] != 0);
    uint8_t kmv = is_u8 ? km_raw[kb] : (uint8_t)(((const int*)km_raw)[kb] != 0);
    const float qy = cq[bq * 3 + 1], qx = cq[bq * 3 + 2];
    const float ky = ck[kb * 3 + 1], kx = ck[kb * 3 + 2];
    float dy = __fsub_rn(qy, ky);
    float dx = __fsub_rn(qx, kx);
    float d2 = __fadd_rn(__fmul_rn(dy, dy), __fmul_rn(dx, dx));
    float dist = __fsqrt_rn(d2);
    int fl = (dist > 0.5f) | qmv | kmv;
    size_t o = (size_t)bq * NKV + kv;
    prior[o] = __expf(-10.f * dist);
    flagb[o] = (uint8_t)fl;
}

// ---------------------------------------------------------------------------
// Segmented fp32->bf16 convert: all 6 buffers in one launch.
// dst regions are contiguous starting at qtb.
// ---------------------------------------------------------------------------
#define S4 ((int)((size_t)NTOK * DD / 4))     // 1179648
#define W4 ((int)((size_t)DD * DD / 4))       // 262144
__global__ __launch_bounds__(256) void f2bf_all_kernel(
    const float* __restrict__ q_tokens, const float* __restrict__ kv_tokens,
    const float* __restrict__ Wq, const float* __restrict__ Wk,
    const float* __restrict__ Wv, const float* __restrict__ Wo,
    ushort* __restrict__ dst0)
{
    int i = blockIdx.x * 256 + threadIdx.x;   // total 2*S4 + 4*W4 exact
    const float* src; int off;
    if (i < 2 * S4) {
        src = (i < S4) ? q_tokens : kv_tokens;
        off = (i < S4) ? i : i - S4;
    } else {
        int j = i - 2 * S4;
        int w = j >> 18;                      // j / W4 (W4 = 2^18)
        src = (w == 0) ? Wq : (w == 1) ? Wk : (w == 2) ? Wv : Wo;
        off = j & (W4 - 1);
    }
    float4 v = ((const float4*)src)[off];
    ushort4 o;
    o.x = f2bf(v.x); o.y = f2bf(v.y); o.z = f2bf(v.z); o.w = f2bf(v.w);
    ((ushort4*)dst0)[i] = o;
}

// ---------------------------------------------------------------------------
// GEMM core (verified R7): BM=64, BN=128, BK=64; T2 slot-swizzled LDS via
// pre-swizzled global source; gld_lds width-16 staging.
// modes: 1 = fp32 row-major; 3 = bf16 transposed [bt,h,dh,tok] (V);
//        4/5 = rope+bf16 scatter [bt,h,tok,dh] (Q/K, cst = csq/csk)
// ---------------------------------------------------------------------------
__device__ __forceinline__ void gemm_core(
    const ushort* __restrict__ X, const ushort* __restrict__ W,
    const float* __restrict__ bias, void* __restrict__ O,
    const float2* __restrict__ cst, const int mode,
    const int m0, const int n0, ushort* As, ushort* Bs)
{
    const int tid = threadIdx.x;
    const int lane = tid & 63, w = tid >> 6;
    const int wm = (w & 1) * 32, wn = (w >> 1) * 64;
    const int frow = lane & 15, quad = lane >> 4;
    const int srow = lane >> 3;
    const int scole = ((lane & 7) ^ srow) << 3;

    f32x4 acc[2][4];
#pragma unroll
    for (int m = 0; m < 2; m++)
#pragma unroll
        for (int n = 0; n < 4; n++) acc[m][n] = (f32x4)0.f;

    for (int k0 = 0; k0 < DD; k0 += 64) {
        __syncthreads();
#pragma unroll
        for (int j = 0; j < 2; j++) {
            int c = w * 2 + j;
            gld_lds16(&X[(size_t)(m0 + c * 8 + srow) * DD + k0 + scole], &As[c * 512]);
        }
#pragma unroll
        for (int j = 0; j < 4; j++) {
            int c = w * 4 + j;
            gld_lds16(&W[(size_t)(n0 + c * 8 + srow) * DD + k0 + scole], &Bs[c * 512]);
        }
        __syncthreads();
        const int rsw = (frow & 7) << 3;
#pragma unroll
        for (int ks = 0; ks < 2; ks++) {
            short8v a[2], b[4];
#pragma unroll
            for (int m = 0; m < 2; m++)
                a[m] = *(const short8v*)&As[(wm + m * 16 + frow) * 64 + ((ks * 32 + quad * 8) ^ rsw)];
#pragma unroll
            for (int n = 0; n < 4; n++)
                b[n] = *(const short8v*)&Bs[(wn + n * 16 + frow) * 64 + ((ks * 32 + quad * 8) ^ rsw)];
#pragma unroll
            for (int m = 0; m < 2; m++)
#pragma unroll
                for (int n = 0; n < 4; n++)
                    acc[m][n] = __builtin_amdgcn_mfma_f32_16x16x32_bf16(
                        a[m], b[n], acc[m][n], 0, 0, 0);
        }
    }

#pragma unroll
    for (int m = 0; m < 2; m++) {
        const int gr0 = m0 + wm + m * 16 + quad * 4;
#pragma unroll
        for (int n = 0; n < 4; n++) {
            const int gc = n0 + wn + n * 16 + frow;
            const float bv_ = bias[gc];
            f32x4 c = acc[m][n];
            if (mode == 1) {
#pragma unroll
                for (int i = 0; i < 4; i++)
                    ((float*)O)[(size_t)(gr0 + i) * DD + gc] = c[i] + bv_;
            } else if (mode == 3) {
                int bt = gr0 / NQ, nn0 = gr0 - bt * NQ;
                int h = gc >> 6, dh = gc & 63;
                ushort4 o4;
                o4.x = f2bf(c[0] + bv_); o4.y = f2bf(c[1] + bv_);
                o4.z = f2bf(c[2] + bv_); o4.w = f2bf(c[3] + bv_);
                *(ushort4*)&((ushort*)O)[(((size_t)(bt * HH + h)) * DH + dh) * NQ + nn0] = o4;
            } else {
                int h = gc >> 6, dh = gc & 63;
                int i2 = dh >> 1;
#pragma unroll
                for (int i = 0; i < 4; i++) {
                    int tok = gr0 + i;
                    float v = c[i] + bv_;
                    float vp = __shfl_xor(v, 1);
                    float2 cs = cst[tok * 32 + i2];
                    float o = (gc & 1) ? (v * cs.x + vp * cs.y)
                                       : (v * cs.x - vp * cs.y);
                    int bt = tok / NQ, nn = tok - bt * NQ;
                    ((ushort*)O)[(((size_t)(bt * HH + h)) * NQ + nn) * DH + dh] = f2bf(o);
                }
            }
        }
    }
}

// ---------------------------------------------------------------------------
// Fused Q/K/V projection GEMM: 1728 blocks. XCD-bijective swizzle: XCD x owns
// global m-tiles [x*27, x*27+27) (all 8 n-tiles each) -> X panel fetched ~once,
// W L2-resident per XCD.
// ---------------------------------------------------------------------------
__global__ __launch_bounds__(256) void gemm_proj3_kernel(
    const ushort* __restrict__ qtb, const ushort* __restrict__ ktb,
    const ushort* __restrict__ Wqb, const ushort* __restrict__ Wkb,
    const ushort* __restrict__ Wvb,
    const float* __restrict__ bq, const float* __restrict__ bk,
    const float* __restrict__ bv,
    ushort* __restrict__ Qh, ushort* __restrict__ Kh, ushort* __restrict__ Vtg,
    const float2* __restrict__ csq, const float2* __restrict__ csk)
{
    __shared__ ushort As[64 * 64];
    __shared__ ushort Bs[128 * 64];
    const int L = blockIdx.x;                 // 1728 = 8 XCD * 216
    const int xcd = L & 7, j = L >> 3;        // j in [0,216)
    const int mt_g = xcd * 27 + (j >> 3);     // global m-tile [0,216)
    const int nt = j & 7;
    const int seg = mt_g / 72;                // 0=Q 1=K 2=V
    const int smt = mt_g - seg * 72;
    const ushort* X = (seg == 0) ? qtb : ktb;
    const ushort* W = (seg == 0) ? Wqb : (seg == 1) ? Wkb : Wvb;
    const float* bias = (seg == 0) ? bq : (seg == 1) ? bk : bv;
    void* O = (seg == 0) ? (void*)Qh : (seg == 1) ? (void*)Kh : (void*)Vtg;
    const float2* cst = (seg == 0) ? csq : csk;
    const int mode = (seg == 0) ? 4 : (seg == 1) ? 5 : 3;
    gemm_core(X, W, bias, O, cst, mode, smt * 64, nt * 128, As, Bs);
}

// ---------------------------------------------------------------------------
// Output GEMM: 576 blocks; XCD x owns m-tiles [x*9, x*9+9).
// ---------------------------------------------------------------------------
__global__ __launch_bounds__(256) void gemm_out_kernel(
    const ushort* __restrict__ Yh, const ushort* __restrict__ Wob,
    const float* __restrict__ bo, float* __restrict__ out)
{
    __shared__ ushort As[64 * 64];
    __shared__ ushort Bs[128 * 64];
    const int L = blockIdx.x;                 // 576 = 8 * 72
    const int xcd = L & 7, j = L >> 3;        // j in [0,72)
    const int mt = xcd * 9 + (j >> 3);
    const int nt = j & 7;
    gemm_core(Yh, Wob, bo, (void*)out, nullptr, 1, mt * 64, nt * 128, As, Bs);
}

// ---------------------------------------------------------------------------
// MFMA flash attention with T14 prefetch (K/V global->reg issued at barrier,
// consumed as ds_write next tile; prior/flag regs prefetched one tile ahead)
// and XCD swizzle (XCD x owns bt=x: all 16 heads x 9 q-tiles).
// ---------------------------------------------------------------------------
__global__ __launch_bounds__(256) void attn_mfma_kernel(
    const ushort* __restrict__ Qh, const ushort* __restrict__ Kh,
    const ushort* __restrict__ Vtg,
    const float* __restrict__ prior, const uint8_t* __restrict__ flagb,
    const float* __restrict__ alpha, ushort* __restrict__ Yh)
{
    __shared__ ushort Ks[64][72];        // [kv][dh]
    __shared__ ushort Vt[64][72];        // [dh][kv]
    __shared__ ushort Ps[4][16][88];     // per-wave [q][kv]

    const int tid = threadIdx.x;
    const int lane = tid & 63, w = tid >> 6;
    const int quad = lane >> 4, l15 = lane & 15;

    const int L = blockIdx.x;            // 1152 = 8 XCD * 144
    const int xcd = L & 7;
    const int logical = xcd * 144 + (L >> 3);
    const int bh = logical / 9;          // [0,128): bt = bh>>4 == xcd
    const int qt = logical - bh * 9;
    const int bt = bh >> 4, h = bh & 15;
    const int q0 = qt * 64;

    const size_t hb = ((size_t)(bt * HH + h)) * NQ * DH;
    const size_t vbs = ((size_t)(bt * HH + h)) * DH * NQ;
    const int qg = q0 + w * 16 + l15;

    const ushort* qrow = Qh + hb + (size_t)qg * DH;
    short8v qf0 = *(const short8v*)(qrow + quad * 8);
    short8v qf1 = *(const short8v*)(qrow + 32 + quad * 8);

    const float alph = alpha[h];
    const size_t pbase = ((size_t)(bt * NQ + qg)) * NKV + quad * 4;

    // staging role: krow = row in Ks (kv) / Vt (dh); 16B x2 per thread
    const int krow = tid >> 2, kcol = (tid & 3) * 16;
    const ushort* Ksrc = Kh + hb + (size_t)krow * DH + kcol;
    const ushort* Vsrc = Vtg + vbs + (size_t)krow * NQ + kcol;

    // prologue: tile 0 K/V regs + prior/flag regs
    short8v ka0 = *(const short8v*)(Ksrc);
    short8v ka1 = *(const short8v*)(Ksrc + 8);
    short8v va0 = *(const short8v*)(Vsrc);
    short8v va1 = *(const short8v*)(Vsrc + 8);
    float4 prf[4]; uint32_t pfl[4];
#pragma unroll
    for (int jt = 0; jt < 4; jt++) {
        prf[jt] = *(const float4*)&prior[pbase + jt * 16];
        pfl[jt] = *(const uint32_t*)&flagb[pbase + jt * 16];
    }

    float m_run = -INFINITY, l_run = 0.f;
    f32x4 oacc[4];
#pragma unroll
    for (int i = 0; i < 4; i++) oacc[i] = (f32x4)0.f;

    for (int kt = 0; kt < 9; kt++) {
        __syncthreads();   // prev tile's LDS reads complete
        *(short8v*)&Ks[krow][kcol]     = ka0;
        *(short8v*)&Ks[krow][kcol + 8] = ka1;
        *(short8v*)&Vt[krow][kcol]     = va0;
        *(short8v*)&Vt[krow][kcol + 8] = va1;
        if (kt < 8) {   // issue next-tile loads; vmcnt waits land before next ds_write
            const ushort* nk = Ksrc + (size_t)(kt + 1) * 64 * DH;
            const ushort* nv = Vsrc + (size_t)(kt + 1) * 64;
            ka0 = *(const short8v*)(nk);
            ka1 = *(const short8v*)(nk + 8);
            va0 = *(const short8v*)(nv);
            va1 = *(const short8v*)(nv + 8);
        }
        __syncthreads();   // staged tile visible

        // QK^T: D[kv_local, q]
        f32x4 sc[4];
#pragma unroll
        for (int jt = 0; jt < 4; jt++) sc[jt] = (f32x4)0.f;
#pragma unroll
        for (int jt = 0; jt < 4; jt++) {
            short8v kf0 = *(const short8v*)&Ks[jt * 16 + l15][quad * 8];
            short8v kf1 = *(const short8v*)&Ks[jt * 16 + l15][32 + quad * 8];
            sc[jt] = __builtin_amdgcn_mfma_f32_16x16x32_bf16(kf0, qf0, sc[jt], 0, 0, 0);
            sc[jt] = __builtin_amdgcn_mfma_f32_16x16x32_bf16(kf1, qf1, sc[jt], 0, 0, 0);
        }

        // bias from prefetched regs; then issue prior prefetch for kt+1
        float p[16];
        float mloc = -INFINITY;
#pragma unroll
        for (int jt = 0; jt < 4; jt++) {
#pragma unroll
            for (int r = 0; r < 4; r++) {
                float prv = (r == 0) ? prf[jt].x : (r == 1) ? prf[jt].y
                          : (r == 2) ? prf[jt].z : prf[jt].w;
                uint8_t fl = (uint8_t)(pfl[jt] >> (8 * r));
                float s = sc[jt][r] * 0.125f + (fl ? NEGV : alph * prv);
                p[jt * 4 + r] = s;
                mloc = fmaxf(mloc, s);
            }
        }
        if (kt < 8) {
            const size_t nb = pbase + (size_t)(kt + 1) * 64;
#pragma unroll
            for (int jt = 0; jt < 4; jt++) {
                prf[jt] = *(const float4*)&prior[nb + jt * 16];
                pfl[jt] = *(const uint32_t*)&flagb[nb + jt * 16];
            }
        }
        mloc = fmaxf(mloc, __shfl_xor(mloc, 16));
        mloc = fmaxf(mloc, __shfl_xor(mloc, 32));
        float m_new = fmaxf(m_run, mloc);
        float scale = __expf(m_run - m_new);    // first iter: exp(-inf)=0
        float psum = 0.f;
#pragma unroll
        for (int i = 0; i < 16; i++) {
            float pv = __expf(p[i] - m_new);    // all-NEG row -> uniform
            p[i] = pv;
            psum += pv;
        }
        psum += __shfl_xor(psum, 16);
        psum += __shfl_xor(psum, 32);
        l_run = l_run * scale + psum;
        m_run = m_new;

        float sr[4];
#pragma unroll
        for (int r = 0; r < 4; r++) sr[r] = __shfl(scale, quad * 4 + r);
#pragma unroll
        for (int tdh = 0; tdh < 4; tdh++)
#pragma unroll
            for (int r = 0; r < 4; r++) oacc[tdh][r] *= sr[r];

        // P -> LDS bf16 transpose to [q][kv]
#pragma unroll
        for (int jt = 0; jt < 4; jt++) {
#pragma unroll
            for (int rp = 0; rp < 2; rp++) {
                uint32_t pk = (uint32_t)f2bf(p[jt * 4 + 2 * rp]) |
                              ((uint32_t)f2bf(p[jt * 4 + 2 * rp + 1]) << 16);
                *(uint32_t*)&Ps[w][l15][jt * 16 + quad * 4 + 2 * rp] = pk;
            }
        }
        // wave-private RAW through LDS: compiler inserts lgkmcnt wait

        short8v pa0 = *(const short8v*)&Ps[w][l15][quad * 8];
        short8v pa1 = *(const short8v*)&Ps[w][l15][32 + quad * 8];
#pragma unroll
        for (int tdh = 0; tdh < 4; tdh++) {
            short8v vb0 = *(const short8v*)&Vt[tdh * 16 + l15][quad * 8];
            short8v vb1 = *(const short8v*)&Vt[tdh * 16 + l15][32 + quad * 8];
            oacc[tdh] = __builtin_amdgcn_mfma_f32_16x16x32_bf16(pa0, vb0, oacc[tdh], 0, 0, 0);
            oacc[tdh] = __builtin_amdgcn_mfma_f32_16x16x32_bf16(pa1, vb1, oacc[tdh], 0, 0, 0);
        }
    }

    float linv = 1.0f / l_run;
    float li[4];
#pragma unroll
    for (int r = 0; r < 4; r++) li[r] = __shfl(linv, quad * 4 + r);
#pragma unroll
    for (int tdh = 0; tdh < 4; tdh++) {
#pragma unroll
        for (int r = 0; r < 4; r++) {
            int tok = bt * NQ + q0 + w * 16 + quad * 4 + r;
            Yh[(size_t)tok * DD + h * DH + tdh * 16 + l15] = f2bf(oacc[tdh][r] * li[r]);
        }
    }
}

// ---------------------------------------------------------------------------
extern "C" void kernel_launch(void* const* d_in, const int* in_sizes, int n_in,
                              void* d_out, int out_size, void* d_ws, size_t ws_size,
                              hipStream_t stream)
{
    const float*   q_tokens  = (const float*)d_in[0];
    const float*   kv_tokens = (const float*)d_in[1];
    const float*   coords_q  = (const float*)d_in[2];
    const float*   coords_k  = (const float*)d_in[3];
    const uint8_t* q_pad     = (const uint8_t*)d_in[4];
    const uint8_t* kv_pad    = (const uint8_t*)d_in[5];
    const float*   Wq = (const float*)d_in[6];
    const float*   bq = (const float*)d_in[7];
    const float*   Wk = (const float*)d_in[8];
    const float*   bk = (const float*)d_in[9];
    const float*   Wv = (const float*)d_in[10];
    const float*   bv = (const float*)d_in[11];
    const float*   Wo = (const float*)d_in[12];
    const float*   bo = (const float*)d_in[13];
    const float*   alpha = (const float*)d_in[14];
    const float*   f0 = (const float*)d_in[15];
    const float*   f1 = (const float*)d_in[16];
    const float*   f2 = (const float*)d_in[17];
    float* out = (float*)d_out;

    const size_t SZ = (size_t)NTOK * DD;     // 4718592
    const size_t WSZ = (size_t)DD * DD;      // 1048576
    float2*  csq  = (float2*)d_ws;
    float2*  csk  = csq + (size_t)NTOK * 32;
    float*   prior = (float*)(csk + (size_t)NTOK * 32);
    ushort*  qtb  = (ushort*)(prior + NPAIR);
    ushort*  ktb  = qtb + SZ;
    ushort*  Wqb  = ktb + SZ;
    ushort*  Wkb  = Wqb + WSZ;
    ushort*  Wvb  = Wkb + WSZ;
    ushort*  Wob  = Wvb + WSZ;
    ushort*  Qh   = Wob + WSZ;
    ushort*  Kh   = Qh + SZ;
    ushort*  Vtg  = Kh + SZ;
    ushort*  Yh   = Vtg + SZ;
    uint8_t* flagb = (uint8_t*)(Yh + SZ);

    build_cs_kernel<<<(2 * NTOK * 32) / 256, 256, 0, stream>>>(
        coords_q, coords_k, f0, f1, f2, csq, csk);

    prior_kernel<<<NTOK, 576, 0, stream>>>(
        coords_q, coords_k, q_pad, kv_pad, prior, flagb);

    f2bf_all_kernel<<<(2 * S4 + 4 * W4) / 256, 256, 0, stream>>>(
        q_tokens, kv_tokens, Wq, Wk, Wv, Wo, qtb);

    gemm_proj3_kernel<<<1728, 256, 0, stream>>>(
        qtb, ktb, Wqb, Wkb, Wvb, bq, bk, bv, Qh, Kh, Vtg, csq, csk);

    attn_mfma_kernel<<<1152, 256, 0, stream>>>(
        Qh, Kh, Vtg, prior, flagb, alpha, Yh);

    gemm_out_kernel<<<576, 256, 0, stream>>>(Yh, Wob, bo, out);
}